// Round 5
// baseline (388.004 us; speedup 1.0000x reference)
//
#include <hip/hip_runtime.h>
#include <hip/hip_cooperative_groups.h>
#include <math.h>

namespace cg = cooperative_groups;

#define B_N 131072
#define CB 256        // cooperative grid blocks
#define CT 256        // threads per block

// ---------------- cooperative ws layout (float offsets) ----------------
// part1[256][352], mom[352], part2[256][40], bn2s[40]
#define CW_P1   0
#define CW_MOM  (256 * 352)              // 90112
#define CW_P2   (CW_MOM + 352)           // 90464
#define CW_BN2  (CW_P2 + 256 * 40)       // 100704

// ---------------- fallback ws layout (round-2, known good) ----------------
#define WS_STAT1 0
#define ST1_SZ   (64 * 352)
#define WS_MT    22528
#define WS_C     23808
#define WS_STAT2 23840
#define WS_NH    26400
#define WS_Z2    26816

__device__ __forceinline__ float gelu_exact(float v) {
    return 0.5f * v * (1.0f + erff(v * 0.70710678118654752440f));
}

// ======================= cooperative mega-kernel =======================
__global__ __launch_bounds__(256, 1) void k_fused(
    const float* __restrict__ x, const float* __restrict__ cen,
    const float* __restrict__ lw, const float* __restrict__ rw,
    const float* __restrict__ linw, const float* __restrict__ Wp,
    const float* __restrict__ pb, const float* __restrict__ g1,
    const float* __restrict__ b1, const float* __restrict__ fpW,
    const float* __restrict__ fpb, const float* __restrict__ g2,
    const float* __restrict__ b2, const float* __restrict__ fzc,
    const float* __restrict__ lsu, const float* __restrict__ lsl,
    const float* __restrict__ hW, const float* __restrict__ hb,
    float* __restrict__ ws, float* __restrict__ out)
{
    __shared__ float sAcc[4][8][44];
    __shared__ __align__(16) float4 sRbf[64];
    __shared__ float sLin[8];
    __shared__ __align__(16) float sMt[1280];
    __shared__ float sC[20], a_[128], bb_[128];
    __shared__ __align__(16) float4 sFz[200];
    __shared__ float sHW[10], sT[40], sSc[20], sSh[20];
    __shared__ float sRed[4][40];

    cg::grid_group grid = cg::this_grid();
    const int t = threadIdx.x;
    const int b = blockIdx.x;
    float* part1 = ws + CW_P1;
    float* mom   = ws + CW_MOM;
    float* part2 = ws + CW_P2;
    float* bn2s  = ws + CW_BN2;

    // ---------------- phase A: act moments -> per-block partials ----------------
    {
        const int g = t & 7, rl = t >> 3;
        float c_[8], nh_[8], w_[8];
#pragma unroll
        for (int k = 0; k < 8; ++k) {
            c_[k] = cen[g * 8 + k];
            float s = expf(lw[g * 8 + k]) + 1e-6f;
            nh_[k] = -0.5f / (s * s);
            w_[k] = rw[g * 8 + k];
        }
        const float lin = linw[g];
        float sumA[8], P[36];
#pragma unroll
        for (int f = 0; f < 8; ++f) sumA[f] = 0.0f;
#pragma unroll
        for (int i = 0; i < 36; ++i) P[i] = 0.0f;

        for (int row = b * 32 + rl; row < B_N; row += CB * 32) {
            const float* xr = x + (size_t)row * 64 + g * 8;
            float4 v0 = *(const float4*)(xr);
            float4 v1 = *(const float4*)(xr + 4);
            float xv[8] = {v0.x, v0.y, v0.z, v0.w, v1.x, v1.y, v1.z, v1.w};
            float act[8];
#pragma unroll
            for (int f = 0; f < 8; ++f) {
                float v = xv[f];
                float a = lin * v;
#pragma unroll
                for (int k = 0; k < 8; ++k) {
                    float d = v - c_[k];
                    a += w_[k] * __expf(d * d * nh_[k]);
                }
                act[f] = a;
            }
            int idx = 0;
#pragma unroll
            for (int f = 0; f < 8; ++f) {
                sumA[f] += act[f];
#pragma unroll
                for (int f2 = 0; f2 <= f; ++f2) { P[idx] += act[f] * act[f2]; ++idx; }
            }
        }
#pragma unroll
        for (int off = 32; off >= 8; off >>= 1) {
#pragma unroll
            for (int f = 0; f < 8; ++f) sumA[f] += __shfl_down(sumA[f], off, 64);
#pragma unroll
            for (int i = 0; i < 36; ++i) P[i] += __shfl_down(P[i], off, 64);
        }
        const int wave = t >> 6, lane = t & 63;
        if (lane < 8) {   // lane == g for these lanes
            float* dst = &sAcc[wave][lane][0];
#pragma unroll
            for (int f = 0; f < 8; ++f) dst[f] = sumA[f];
#pragma unroll
            for (int i = 0; i < 36; ++i) dst[8 + i] = P[i];
        }
        __syncthreads();
        for (int i = t; i < 352; i += 256) {
            int gg = i / 44, v = i % 44;
            part1[b * 352 + i] =
                sAcc[0][gg][v] + sAcc[1][gg][v] + sAcc[2][gg][v] + sAcc[3][gg][v];
        }
    }
    __threadfence();
    grid.sync();

    // ---------------- R1: reduce 256 partials per moment value -> MEAN ----------------
    for (int v = b; v < 352; v += CB) {
        float val = part1[(size_t)t * 352 + v];
#pragma unroll
        for (int off = 32; off >= 1; off >>= 1) val += __shfl_down(val, off, 64);
        if ((t & 63) == 0) sT[t >> 6] = val;
        __syncthreads();
        if (t == 0)
            mom[v] = (sT[0] + sT[1] + sT[2] + sT[3]) * (1.0f / B_N);  // FIX: /B
        __syncthreads();
    }
    __threadfence();
    grid.sync();

    // ---------------- build: BN1 fold -> sMt/sC, RBF + fuzzy tables ----------------
    if (t < 128) {
        const int g = t >> 4;
        float wv[8], Amg[8];
#pragma unroll
        for (int f = 0; f < 8; ++f) { wv[f] = Wp[t * 8 + f]; Amg[f] = mom[g * 44 + f]; }
        float dot = 0.0f;
#pragma unroll
        for (int f = 0; f < 8; ++f) dot += wv[f] * Amg[f];
        const float pbv = pb[t];
        const float mu = pbv + dot;
        float e2 = pbv * pbv + 2.0f * pbv * dot;
        int idx = 0;
#pragma unroll
        for (int f = 0; f < 8; ++f)
#pragma unroll
            for (int f2 = 0; f2 <= f; ++f2) {
                float c2 = (f2 == f) ? 1.0f : 2.0f;
                e2 += c2 * wv[f] * wv[f2] * mom[g * 44 + 8 + idx]; ++idx;
            }
        const float var = fmaxf(e2 - mu * mu, 0.0f);
        const float a = g1[t] * rsqrtf(var + 1e-5f);
        a_[t] = a;
        bb_[t] = b1[t] - mu * a;
    }
    if (t < 64) {
        float s = expf(lw[t]) + 1e-6f;
        sRbf[t] = make_float4(cen[t], rw[t], -0.5f / (s * s), 0.0f);
    }
    if (t < 8)  sLin[t] = linw[t];
    if (t < 10) sHW[t] = hW[t];
    for (int i = t; i < 200; i += 256) {
        float su = expf(lsu[i]) + 1e-6f;
        float sl = fminf(expf(lsl[i]) + 1e-6f, 0.9f * su);
        sFz[i] = make_float4(fzc[i], -0.5f / (su * su), -0.5f / (sl * sl), 0.0f);
    }
    __syncthreads();
    for (int i = t; i < 1280; i += 256) {
        int gf = i / 20, j = i % 20;
        int g = gf >> 3, f = gf & 7;
        float m = 0.0f;
        for (int o = 0; o < 16; ++o) {
            int c = g * 16 + o;
            m += fpW[j * 128 + c] * a_[c] * Wp[c * 8 + f];
        }
        sMt[i] = m;
    }
    if (t < 20) {
        float cj = fpb[t];
        for (int c = 0; c < 128; ++c)
            cj += fpW[t * 128 + c] * (a_[c] * pb[c] + bb_[c]);
        sC[t] = cj;
    }
    __syncthreads();

    // ---------------- phase B: z (2 rows/thread, kept in registers) ----------------
    const int r0 = (b * CT + t) * 2;
    float z[2][20];
#pragma unroll
    for (int j = 0; j < 20; ++j) { z[0][j] = sC[j]; z[1][j] = sC[j]; }
    {
        const float* xr = x + (size_t)r0 * 64;
#pragma unroll 1
        for (int g = 0; g < 8; ++g) {
            float4 p0 = *(const float4*)(xr + g * 8);
            float4 p1 = *(const float4*)(xr + g * 8 + 4);
            float4 q0 = *(const float4*)(xr + 64 + g * 8);
            float4 q1 = *(const float4*)(xr + 64 + g * 8 + 4);
            float xv[2][8] = {{p0.x, p0.y, p0.z, p0.w, p1.x, p1.y, p1.z, p1.w},
                              {q0.x, q0.y, q0.z, q0.w, q1.x, q1.y, q1.z, q1.w}};
            float act[2][8];
            float lin = sLin[g];
#pragma unroll
            for (int r = 0; r < 2; ++r)
#pragma unroll
                for (int f = 0; f < 8; ++f) act[r][f] = lin * xv[r][f];
#pragma unroll 1
            for (int k = 0; k < 8; ++k) {
                float4 p = sRbf[g * 8 + k];
#pragma unroll
                for (int r = 0; r < 2; ++r)
#pragma unroll
                    for (int f = 0; f < 8; ++f) {
                        float d = xv[r][f] - p.x;
                        act[r][f] += p.y * __expf(d * d * p.z);
                    }
            }
#pragma unroll 1
            for (int f = 0; f < 8; ++f) {
                const float4* m4 = (const float4*)(sMt + (g * 8 + f) * 20);
                float4 ma = m4[0], mb = m4[1], mc = m4[2], md = m4[3], me = m4[4];
#pragma unroll
                for (int r = 0; r < 2; ++r) {
                    float av = act[r][f];
                    z[r][0] += av * ma.x; z[r][1] += av * ma.y; z[r][2] += av * ma.z; z[r][3] += av * ma.w;
                    z[r][4] += av * mb.x; z[r][5] += av * mb.y; z[r][6] += av * mb.z; z[r][7] += av * mb.w;
                    z[r][8] += av * mc.x; z[r][9] += av * mc.y; z[r][10] += av * mc.z; z[r][11] += av * mc.w;
                    z[r][12] += av * md.x; z[r][13] += av * md.y; z[r][14] += av * md.z; z[r][15] += av * md.w;
                    z[r][16] += av * me.x; z[r][17] += av * me.y; z[r][18] += av * me.z; z[r][19] += av * me.w;
                }
            }
        }
    }
    // BN2 partial stats
    {
        float s_[20], q_[20];
#pragma unroll
        for (int j = 0; j < 20; ++j) {
            s_[j] = z[0][j] + z[1][j];
            q_[j] = z[0][j] * z[0][j] + z[1][j] * z[1][j];
        }
#pragma unroll
        for (int off = 32; off >= 1; off >>= 1) {
#pragma unroll
            for (int j = 0; j < 20; ++j) {
                s_[j] += __shfl_down(s_[j], off, 64);
                q_[j] += __shfl_down(q_[j], off, 64);
            }
        }
        const int wave = t >> 6, lane = t & 63;
        if (lane == 0) {
#pragma unroll
            for (int j = 0; j < 20; ++j) {
                sRed[wave][j] = s_[j];
                sRed[wave][20 + j] = q_[j];
            }
        }
        __syncthreads();
        if (t < 40)
            part2[b * 40 + t] = sRed[0][t] + sRed[1][t] + sRed[2][t] + sRed[3][t];
    }
    __threadfence();
    grid.sync();

    // ---------------- R2: reduce BN2 partials ----------------
    if (b < 40) {
        float val = part2[(size_t)t * 40 + b];
#pragma unroll
        for (int off = 32; off >= 1; off >>= 1) val += __shfl_down(val, off, 64);
        if ((t & 63) == 0) sT[t >> 6] = val;
        __syncthreads();
        if (t == 0) bn2s[b] = sT[0] + sT[1] + sT[2] + sT[3];
    }
    __threadfence();
    grid.sync();

    // ---------------- phase C: BN2 + GELU + fuzzy + head ----------------
    if (t < 40) sT[t] = bn2s[t];
    __syncthreads();
    if (t < 20) {
        float mu = sT[t] * (1.0f / B_N);
        float var = fmaxf(sT[20 + t] * (1.0f / B_N) - mu * mu, 0.0f);
        float sc = g2[t] * rsqrtf(var + 1e-5f);
        sSc[t] = sc;
        sSh[t] = b2[t] - mu * sc;
    }
    __syncthreads();
#pragma unroll
    for (int r = 0; r < 2; ++r)
#pragma unroll
        for (int j = 0; j < 20; ++j)
            z[r][j] = gelu_exact(sSc[j] * z[r][j] + sSh[j]);
    const float hbv = hb[0];
    float acc0 = hbv, acc1 = hbv;
#pragma unroll 1
    for (int r = 0; r < 10; ++r) {
        float u0 = 0.0f, l0 = 0.0f, u1 = 0.0f, l1 = 0.0f;
#pragma unroll
        for (int j = 0; j < 20; ++j) {
            float4 p = sFz[r * 20 + j];
            float d0 = z[0][j] - p.x, d1 = z[1][j] - p.x;
            float dd0 = d0 * d0, dd1 = d1 * d1;
            u0 += __expf(dd0 * p.y); l0 += __expf(dd0 * p.z);
            u1 += __expf(dd1 * p.y); l1 += __expf(dd1 * p.z);
        }
        float w = sHW[r] * 0.025f;
        acc0 += w * (u0 + l0);
        acc1 += w * (u1 + l1);
    }
    *(float2*)(out + r0) = make_float2(acc0, acc1);
}

// ======================= fallback pipeline (round-2 mode 1) =======================
__global__ __launch_bounds__(256) void k_act_moments(
    const float* __restrict__ x, const float* __restrict__ cen,
    const float* __restrict__ lw, const float* __restrict__ rw,
    const float* __restrict__ linw, float* __restrict__ stat1)
{
    __shared__ float sAcc[4][8][44];
    const int t = threadIdx.x;
    const int g = t & 7;
    const int rl = t >> 3;
    float c_[8], nh_[8], w_[8];
#pragma unroll
    for (int k = 0; k < 8; ++k) {
        c_[k] = cen[g * 8 + k];
        float s = expf(lw[g * 8 + k]) + 1e-6f;
        nh_[k] = -0.5f / (s * s);
        w_[k] = rw[g * 8 + k];
    }
    const float lin = linw[g];
    float sumA[8], P[36];
#pragma unroll
    for (int f = 0; f < 8; ++f) sumA[f] = 0.0f;
#pragma unroll
    for (int i = 0; i < 36; ++i) P[i] = 0.0f;
    for (int row = blockIdx.x * 32 + rl; row < B_N; row += gridDim.x * 32) {
        const float* xr = x + (size_t)row * 64 + g * 8;
        float4 v0 = *(const float4*)(xr);
        float4 v1 = *(const float4*)(xr + 4);
        float xv[8] = {v0.x, v0.y, v0.z, v0.w, v1.x, v1.y, v1.z, v1.w};
        float act[8];
#pragma unroll
        for (int f = 0; f < 8; ++f) {
            float v = xv[f];
            float a = lin * v;
#pragma unroll
            for (int k = 0; k < 8; ++k) {
                float d = v - c_[k];
                a += w_[k] * __expf(d * d * nh_[k]);
            }
            act[f] = a;
        }
        int idx = 0;
#pragma unroll
        for (int f = 0; f < 8; ++f) {
            sumA[f] += act[f];
#pragma unroll
            for (int f2 = 0; f2 <= f; ++f2) { P[idx] += act[f] * act[f2]; ++idx; }
        }
    }
#pragma unroll
    for (int off = 32; off >= 8; off >>= 1) {
#pragma unroll
        for (int f = 0; f < 8; ++f) sumA[f] += __shfl_down(sumA[f], off, 64);
#pragma unroll
        for (int i = 0; i < 36; ++i) P[i] += __shfl_down(P[i], off, 64);
    }
    const int wave = t >> 6, lane = t & 63;
    if (lane < 8) {
        float* dst = &sAcc[wave][lane][0];
#pragma unroll
        for (int f = 0; f < 8; ++f) dst[f] = sumA[f];
#pragma unroll
        for (int i = 0; i < 36; ++i) dst[8 + i] = P[i];
    }
    __syncthreads();
    for (int i = t; i < 352; i += 256) {
        int gg = i / 44, v = i % 44;
        float s = sAcc[0][gg][v] + sAcc[1][gg][v] + sAcc[2][gg][v] + sAcc[3][gg][v];
        atomicAdd(&stat1[(blockIdx.x & 63) * 352 + i], s);
    }
}

__global__ __launch_bounds__(256) void k_build(
    const float* __restrict__ stat1, const float* __restrict__ fpW,
    const float* __restrict__ fpb, const float* __restrict__ g1,
    const float* __restrict__ b1, const float* __restrict__ Wp,
    const float* __restrict__ pb, const float* __restrict__ lsu,
    const float* __restrict__ lsl,
    float* __restrict__ Mt, float* __restrict__ Cc, float* __restrict__ nh,
    float* __restrict__ stat2)
{
    __shared__ float Am[8][8];
    __shared__ float Sg[8][36];
    __shared__ float a_[128], bb_[128];
    const int t = threadIdx.x;
    for (int i = t; i < 352; i += 256) {
        float s = 0.0f;
        for (int st = 0; st < 64; ++st) s += stat1[st * 352 + i];
        float m = s * (1.0f / B_N);
        int g = i / 44, v = i % 44;
        if (v < 8) Am[g][v] = m; else Sg[g][v - 8] = m;
    }
    __syncthreads();
    if (t < 128) {
        const int g = t >> 4;
        float wv[8];
#pragma unroll
        for (int f = 0; f < 8; ++f) wv[f] = Wp[t * 8 + f];
        float dot = 0.0f;
#pragma unroll
        for (int f = 0; f < 8; ++f) dot += wv[f] * Am[g][f];
        const float pbv = pb[t];
        const float mu = pbv + dot;
        float e2 = pbv * pbv + 2.0f * pbv * dot;
        int idx = 0;
#pragma unroll
        for (int f = 0; f < 8; ++f)
#pragma unroll
            for (int f2 = 0; f2 <= f; ++f2) {
                float c2 = (f2 == f) ? 1.0f : 2.0f;
                e2 += c2 * wv[f] * wv[f2] * Sg[g][idx]; ++idx;
            }
        const float var = fmaxf(e2 - mu * mu, 0.0f);
        const float a = g1[t] * rsqrtf(var + 1e-5f);
        a_[t] = a;
        bb_[t] = b1[t] - mu * a;
    }
    __syncthreads();
    for (int i = t; i < 1280; i += 256) {
        int gf = i / 20, j = i % 20;
        int g = gf >> 3, f = gf & 7;
        float m = 0.0f;
        for (int o = 0; o < 16; ++o) {
            int c = g * 16 + o;
            m += fpW[j * 128 + c] * a_[c] * Wp[c * 8 + f];
        }
        Mt[i] = m;
    }
    if (t < 20) {
        float cj = fpb[t];
        for (int c = 0; c < 128; ++c)
            cj += fpW[t * 128 + c] * (a_[c] * pb[c] + bb_[c]);
        Cc[t] = cj;
    }
    for (int i = t; i < 200; i += 256) {
        float su = expf(lsu[i]) + 1e-6f;
        float sl = fminf(expf(lsl[i]) + 1e-6f, 0.9f * su);
        nh[i] = -0.5f / (su * su);
        nh[200 + i] = -0.5f / (sl * sl);
    }
    for (int i = t; i < 2560; i += 256) stat2[i] = 0.0f;
}

__device__ __forceinline__ void zpre_row(
    const float* __restrict__ xr, const float4* __restrict__ sRbf,
    const float* __restrict__ sLin, const float* __restrict__ sMt,
    const float* __restrict__ sC, float zp[20])
{
#pragma unroll
    for (int j = 0; j < 20; ++j) zp[j] = sC[j];
#pragma unroll 1
    for (int g = 0; g < 8; ++g) {
        float4 v0 = *(const float4*)(xr + g * 8);
        float4 v1 = *(const float4*)(xr + g * 8 + 4);
        float xv[8] = {v0.x, v0.y, v0.z, v0.w, v1.x, v1.y, v1.z, v1.w};
        float act[8];
        float lin = sLin[g];
#pragma unroll
        for (int f = 0; f < 8; ++f) act[f] = lin * xv[f];
#pragma unroll 1
        for (int k = 0; k < 8; ++k) {
            float4 p = sRbf[g * 8 + k];
#pragma unroll
            for (int f = 0; f < 8; ++f) {
                float d = xv[f] - p.x;
                act[f] += p.y * __expf(d * d * p.z);
            }
        }
#pragma unroll 1
        for (int f = 0; f < 8; ++f) {
            float av = act[f];
            const float4* m4 = (const float4*)(sMt + (g * 8 + f) * 20);
            float4 ma = m4[0], mb = m4[1], mc = m4[2], md = m4[3], me = m4[4];
            zp[0] += av * ma.x; zp[1] += av * ma.y; zp[2] += av * ma.z; zp[3] += av * ma.w;
            zp[4] += av * mb.x; zp[5] += av * mb.y; zp[6] += av * mb.z; zp[7] += av * mb.w;
            zp[8] += av * mc.x; zp[9] += av * mc.y; zp[10] += av * mc.z; zp[11] += av * mc.w;
            zp[12] += av * md.x; zp[13] += av * md.y; zp[14] += av * md.z; zp[15] += av * md.w;
            zp[16] += av * me.x; zp[17] += av * me.y; zp[18] += av * me.z; zp[19] += av * me.w;
        }
    }
}

__global__ __launch_bounds__(256) void k_zpre_stats(
    const float* __restrict__ x, const float* __restrict__ cen,
    const float* __restrict__ lw, const float* __restrict__ rw,
    const float* __restrict__ linw, const float* __restrict__ Mt,
    const float* __restrict__ Cc, float* __restrict__ zout,
    float* __restrict__ stat2)
{
    __shared__ __align__(16) float4 sRbf[64];
    __shared__ float sLin[8], sC[20];
    __shared__ __align__(16) float sMt[1280];
    __shared__ float sRed[4][40];
    const int t = threadIdx.x;
    if (t < 64) {
        float s = expf(lw[t]) + 1e-6f;
        sRbf[t] = make_float4(cen[t], rw[t], -0.5f / (s * s), 0.0f);
    }
    if (t < 8)  sLin[t] = linw[t];
    if (t < 20) sC[t] = Cc[t];
    for (int i = t; i < 1280; i += 256) sMt[i] = Mt[i];
    __syncthreads();
    const int row = blockIdx.x * 256 + t;
    float zp[20];
    zpre_row(x + (size_t)row * 64, sRbf, sLin, sMt, sC, zp);
#pragma unroll
    for (int j = 0; j < 20; ++j) zout[(size_t)j * B_N + row] = zp[j];
    float s_[20], q_[20];
#pragma unroll
    for (int j = 0; j < 20; ++j) { s_[j] = zp[j]; q_[j] = zp[j] * zp[j]; }
#pragma unroll
    for (int off = 32; off >= 1; off >>= 1) {
#pragma unroll
        for (int j = 0; j < 20; ++j) {
            s_[j] += __shfl_down(s_[j], off, 64);
            q_[j] += __shfl_down(q_[j], off, 64);
        }
    }
    const int wave = t >> 6, lane = t & 63;
    if (lane == 0) {
#pragma unroll
        for (int j = 0; j < 20; ++j) { sRed[wave][j] = s_[j]; sRed[wave][20 + j] = q_[j]; }
    }
    __syncthreads();
    if (t < 40) {
        float v = sRed[0][t] + sRed[1][t] + sRed[2][t] + sRed[3][t];
        atomicAdd(&stat2[(blockIdx.x & 63) * 40 + t], v);
    }
}

__global__ __launch_bounds__(256) void k_out2(
    const float* __restrict__ zin, const float* __restrict__ stat2,
    const float* __restrict__ g2, const float* __restrict__ b2,
    const float* __restrict__ nh, const float* __restrict__ fzc,
    const float* __restrict__ hW, const float* __restrict__ hb,
    float* __restrict__ out)
{
    __shared__ float sT[40], sSc[20], sSh[20], sHW[10];
    __shared__ __align__(16) float4 sFz[200];
    const int t = threadIdx.x;
    if (t < 10) sHW[t] = hW[t];
    for (int i = t; i < 200; i += 256)
        sFz[i] = make_float4(fzc[i], nh[i], nh[200 + i], 0.0f);
    if (t < 40) {
        float s = 0.0f;
        for (int st = 0; st < 64; ++st) s += stat2[st * 40 + t];
        sT[t] = s;
    }
    __syncthreads();
    if (t < 20) {
        float mu = sT[t] * (1.0f / B_N);
        float var = fmaxf(sT[20 + t] * (1.0f / B_N) - mu * mu, 0.0f);
        float sc = g2[t] * rsqrtf(var + 1e-5f);
        sSc[t] = sc;
        sSh[t] = b2[t] - mu * sc;
    }
    __syncthreads();
    const int r0 = (blockIdx.x * 256 + t) * 2;
    float z0[20], z1[20];
#pragma unroll
    for (int j = 0; j < 20; ++j) {
        float2 v = *(const float2*)(zin + (size_t)j * B_N + r0);
        z0[j] = gelu_exact(sSc[j] * v.x + sSh[j]);
        z1[j] = gelu_exact(sSc[j] * v.y + sSh[j]);
    }
    const float hbv = hb[0];
    float acc0 = hbv, acc1 = hbv;
#pragma unroll 1
    for (int r = 0; r < 10; ++r) {
        float u0 = 0.0f, l0 = 0.0f, u1 = 0.0f, l1 = 0.0f;
#pragma unroll
        for (int j = 0; j < 20; ++j) {
            float4 p = sFz[r * 20 + j];
            float d0 = z0[j] - p.x, d1 = z1[j] - p.x;
            float dd0 = d0 * d0, dd1 = d1 * d1;
            u0 += __expf(dd0 * p.y); l0 += __expf(dd0 * p.z);
            u1 += __expf(dd1 * p.y); l1 += __expf(dd1 * p.z);
        }
        float w = sHW[r] * 0.025f;
        acc0 += w * (u0 + l0);
        acc1 += w * (u1 + l1);
    }
    *(float2*)(out + r0) = make_float2(acc0, acc1);
}

// ---------------- launcher ----------------
extern "C" void kernel_launch(void* const* d_in, const int* in_sizes, int n_in,
                              void* d_out, int out_size, void* d_ws, size_t ws_size,
                              hipStream_t stream) {
    const float* x    = (const float*)d_in[0];
    const float* cen  = (const float*)d_in[1];
    const float* lw   = (const float*)d_in[2];
    const float* rw   = (const float*)d_in[3];
    const float* linw = (const float*)d_in[4];
    const float* Wp   = (const float*)d_in[5];
    const float* pb   = (const float*)d_in[6];
    const float* g1   = (const float*)d_in[7];
    const float* b1   = (const float*)d_in[8];
    const float* fpW  = (const float*)d_in[9];
    const float* fpb  = (const float*)d_in[10];
    const float* g2   = (const float*)d_in[11];
    const float* b2   = (const float*)d_in[12];
    const float* fzc  = (const float*)d_in[13];
    const float* lsu  = (const float*)d_in[14];
    const float* lsl  = (const float*)d_in[15];
    const float* hW   = (const float*)d_in[16];
    const float* hb   = (const float*)d_in[17];

    float* wsf  = (float*)d_ws;
    float* outp = (float*)d_out;

    // ---- try cooperative single-kernel path ----
    void* args[20] = {
        (void*)&x, (void*)&cen, (void*)&lw, (void*)&rw, (void*)&linw,
        (void*)&Wp, (void*)&pb, (void*)&g1, (void*)&b1, (void*)&fpW,
        (void*)&fpb, (void*)&g2, (void*)&b2, (void*)&fzc, (void*)&lsu,
        (void*)&lsl, (void*)&hW, (void*)&hb, (void*)&wsf, (void*)&outp
    };
    hipError_t e = hipLaunchCooperativeKernel((const void*)k_fused,
                                              dim3(CB), dim3(CT), args, 0, stream);
    if (e == hipSuccess) return;
    (void)hipGetLastError();   // clear sticky error, fall back

    // ---- fallback: 5-dispatch pipeline (round-2 structure) ----
    float* stat1 = wsf + WS_STAT1;
    float* Mt    = wsf + WS_MT;
    float* Cc    = wsf + WS_C;
    float* stat2 = wsf + WS_STAT2;
    float* nh    = wsf + WS_NH;
    float* zbuf  = wsf + WS_Z2;

    hipMemsetAsync(stat1, 0, (size_t)ST1_SZ * sizeof(float), stream);
    k_act_moments<<<1024, 256, 0, stream>>>(x, cen, lw, rw, linw, stat1);
    k_build<<<1, 256, 0, stream>>>(stat1, fpW, fpb, g1, b1, Wp, pb, lsu, lsl,
                                   Mt, Cc, nh, stat2);
    k_zpre_stats<<<512, 256, 0, stream>>>(x, cen, lw, rw, linw, Mt, Cc, zbuf, stat2);
    k_out2<<<256, 256, 0, stream>>>(zbuf, stat2, g2, b2, nh, fzc, hW, hb, outp);
}

// Round 6
// 186.083 us; speedup vs baseline: 2.0851x; 2.0851x over previous
//
#include <hip/hip_runtime.h>
#include <hip/hip_cooperative_groups.h>
#include <math.h>

namespace cg = cooperative_groups;

#define B_N 131072
#define CB 1024       // cooperative grid blocks (4 per CU)
#define CT 256        // threads per block

// ---------------- cooperative ws layout (float offsets), transposed partials ----------------
// part1t[352][CB], mom[352], part2t[40][CB], bn2s[40]
#define CW_P1   0
#define CW_MOM  (352 * CB)               // 360448
#define CW_P2   (CW_MOM + 352)           // 360800
#define CW_BN2  (CW_P2 + 40 * CB)        // 401760

// ---------------- fallback ws layout (round-2, known good) ----------------
#define WS_STAT1 0
#define ST1_SZ   (64 * 352)
#define WS_MT    22528
#define WS_C     23808
#define WS_STAT2 23840
#define WS_NH    26400
#define WS_Z2    26816

__device__ __forceinline__ float gelu_exact(float v) {
    return 0.5f * v * (1.0f + erff(v * 0.70710678118654752440f));
}

// ======================= cooperative mega-kernel (pair-split) =======================
__global__ __launch_bounds__(256, 4) void k_fused(
    const float* __restrict__ x, const float* __restrict__ cen,
    const float* __restrict__ lw, const float* __restrict__ rw,
    const float* __restrict__ linw, const float* __restrict__ Wp,
    const float* __restrict__ pb, const float* __restrict__ g1,
    const float* __restrict__ b1, const float* __restrict__ fpW,
    const float* __restrict__ fpb, const float* __restrict__ g2,
    const float* __restrict__ b2, const float* __restrict__ fzc,
    const float* __restrict__ lsu, const float* __restrict__ lsl,
    const float* __restrict__ hW, const float* __restrict__ hb,
    float* __restrict__ ws, float* __restrict__ out)
{
    __shared__ float sAcc[4][8][44];
    __shared__ __align__(16) float4 sRbf[64];
    __shared__ float sLin[8];
    __shared__ __align__(16) float sMt[1280];
    __shared__ float sC[20], a_[128], bb_[128];
    __shared__ __align__(16) float4 sFz[200];
    __shared__ float sHW[10], sT[40], sSc[20], sSh[20];
    __shared__ float sRed[4][40];

    cg::grid_group grid = cg::this_grid();
    const int t = threadIdx.x;
    const int b = blockIdx.x;
    float* part1t = ws + CW_P1;
    float* mom    = ws + CW_MOM;
    float* part2t = ws + CW_P2;
    float* bn2s   = ws + CW_BN2;

    // ---------------- phase A: act moments -> per-block partials (transposed) ----------------
    {
        const int g = t & 7, rl = t >> 3;
        float c_[8], nh_[8], w_[8];
#pragma unroll
        for (int k = 0; k < 8; ++k) {
            c_[k] = cen[g * 8 + k];
            float s = expf(lw[g * 8 + k]) + 1e-6f;
            nh_[k] = -0.5f / (s * s);
            w_[k] = rw[g * 8 + k];
        }
        const float lin = linw[g];
        float sumA[8], P[36];
#pragma unroll
        for (int f = 0; f < 8; ++f) sumA[f] = 0.0f;
#pragma unroll
        for (int i = 0; i < 36; ++i) P[i] = 0.0f;

#pragma unroll 1
        for (int row = b * 32 + rl; row < B_N; row += CB * 32) {
            const float* xr = x + (size_t)row * 64 + g * 8;
            float4 v0 = *(const float4*)(xr);
            float4 v1 = *(const float4*)(xr + 4);
            float xv[8] = {v0.x, v0.y, v0.z, v0.w, v1.x, v1.y, v1.z, v1.w};
            float act[8];
#pragma unroll
            for (int f = 0; f < 8; ++f) {
                float v = xv[f];
                float a = lin * v;
#pragma unroll
                for (int k = 0; k < 8; ++k) {
                    float d = v - c_[k];
                    a += w_[k] * __expf(d * d * nh_[k]);
                }
                act[f] = a;
            }
            int idx = 0;
#pragma unroll
            for (int f = 0; f < 8; ++f) {
                sumA[f] += act[f];
#pragma unroll
                for (int f2 = 0; f2 <= f; ++f2) { P[idx] += act[f] * act[f2]; ++idx; }
            }
        }
#pragma unroll
        for (int off = 32; off >= 8; off >>= 1) {
#pragma unroll
            for (int f = 0; f < 8; ++f) sumA[f] += __shfl_down(sumA[f], off, 64);
#pragma unroll
            for (int i = 0; i < 36; ++i) P[i] += __shfl_down(P[i], off, 64);
        }
        const int wave = t >> 6, lane = t & 63;
        if (lane < 8) {   // lane == g for these lanes
            float* dst = &sAcc[wave][lane][0];
#pragma unroll
            for (int f = 0; f < 8; ++f) dst[f] = sumA[f];
#pragma unroll
            for (int i = 0; i < 36; ++i) dst[8 + i] = P[i];
        }
        __syncthreads();
        for (int i = t; i < 352; i += 256) {
            int gg = i / 44, v = i % 44;
            part1t[(size_t)i * CB + b] =
                sAcc[0][gg][v] + sAcc[1][gg][v] + sAcc[2][gg][v] + sAcc[3][gg][v];
        }
    }
    __threadfence();
    grid.sync();

    // ---------------- R1: reduce CB partials per moment value -> mean ----------------
    if (b < 352) {
        float val = 0.0f;
#pragma unroll
        for (int p = t; p < CB; p += 256) val += part1t[(size_t)b * CB + p];
#pragma unroll
        for (int off = 32; off >= 1; off >>= 1) val += __shfl_down(val, off, 64);
        if ((t & 63) == 0) sT[t >> 6] = val;
        __syncthreads();
        if (t == 0)
            mom[b] = (sT[0] + sT[1] + sT[2] + sT[3]) * (1.0f / B_N);
    }
    __threadfence();
    grid.sync();

    // ---------------- build: BN1 fold -> sMt/sC, RBF + fuzzy tables ----------------
    if (t < 128) {
        const int g = t >> 4;
        float wv[8], Amg[8];
#pragma unroll
        for (int f = 0; f < 8; ++f) { wv[f] = Wp[t * 8 + f]; Amg[f] = mom[g * 44 + f]; }
        float dot = 0.0f;
#pragma unroll
        for (int f = 0; f < 8; ++f) dot += wv[f] * Amg[f];
        const float pbv = pb[t];
        const float mu = pbv + dot;
        float e2 = pbv * pbv + 2.0f * pbv * dot;
        int idx = 0;
#pragma unroll
        for (int f = 0; f < 8; ++f)
#pragma unroll
            for (int f2 = 0; f2 <= f; ++f2) {
                float c2 = (f2 == f) ? 1.0f : 2.0f;
                e2 += c2 * wv[f] * wv[f2] * mom[g * 44 + 8 + idx]; ++idx;
            }
        const float var = fmaxf(e2 - mu * mu, 0.0f);
        const float a = g1[t] * rsqrtf(var + 1e-5f);
        a_[t] = a;
        bb_[t] = b1[t] - mu * a;
    }
    if (t < 64) {
        float s = expf(lw[t]) + 1e-6f;
        sRbf[t] = make_float4(cen[t], rw[t], -0.5f / (s * s), 0.0f);
    }
    if (t < 8)  sLin[t] = linw[t];
    if (t < 10) sHW[t] = hW[t];
    for (int i = t; i < 200; i += 256) {
        float su = expf(lsu[i]) + 1e-6f;
        float sl = fminf(expf(lsl[i]) + 1e-6f, 0.9f * su);
        sFz[i] = make_float4(fzc[i], -0.5f / (su * su), -0.5f / (sl * sl), 0.0f);
    }
    __syncthreads();
    for (int i = t; i < 1280; i += 256) {
        int gf = i / 20, j = i % 20;
        int g = gf >> 3, f = gf & 7;
        float m = 0.0f;
        for (int o = 0; o < 16; ++o) {
            int c = g * 16 + o;
            m += fpW[j * 128 + c] * a_[c] * Wp[c * 8 + f];
        }
        sMt[i] = m;
    }
    if (t < 20) {
        float cj = fpb[t];
        for (int c = 0; c < 128; ++c)
            cj += fpW[t * 128 + c] * (a_[c] * pb[c] + bb_[c]);
        sC[t] = cj;
    }
    __syncthreads();

    // ---------------- phase B: pair-split z (half row per thread, z in regs) ----------------
    const int pair = b * 128 + (t >> 1);     // row index, CB*128 == B_N
    const int half = t & 1;
    float z[20];
#pragma unroll
    for (int j = 0; j < 20; ++j) z[j] = half ? 0.0f : sC[j];
    {
        const float* xr = x + (size_t)pair * 64 + half * 32;
#pragma unroll 1
        for (int gg = 0; gg < 4; ++gg) {
            const int g = half * 4 + gg;
            float4 v0 = *(const float4*)(xr + gg * 8);
            float4 v1 = *(const float4*)(xr + gg * 8 + 4);
            float xv[8] = {v0.x, v0.y, v0.z, v0.w, v1.x, v1.y, v1.z, v1.w};
            float act[8];
            float lin = sLin[g];
#pragma unroll
            for (int f = 0; f < 8; ++f) act[f] = lin * xv[f];
#pragma unroll 1
            for (int k = 0; k < 8; ++k) {
                float4 p = sRbf[g * 8 + k];
#pragma unroll
                for (int f = 0; f < 8; ++f) {
                    float d = xv[f] - p.x;
                    act[f] += p.y * __expf(d * d * p.z);
                }
            }
#pragma unroll 1
            for (int f = 0; f < 8; ++f) {
                float av = act[f];
                const float4* m4 = (const float4*)(sMt + (g * 8 + f) * 20);
                float4 ma = m4[0], mb = m4[1], mc = m4[2], md = m4[3], me = m4[4];
                z[0] += av * ma.x; z[1] += av * ma.y; z[2] += av * ma.z; z[3] += av * ma.w;
                z[4] += av * mb.x; z[5] += av * mb.y; z[6] += av * mb.z; z[7] += av * mb.w;
                z[8] += av * mc.x; z[9] += av * mc.y; z[10] += av * mc.z; z[11] += av * mc.w;
                z[12] += av * md.x; z[13] += av * md.y; z[14] += av * md.z; z[15] += av * md.w;
                z[16] += av * me.x; z[17] += av * me.y; z[18] += av * me.z; z[19] += av * me.w;
            }
        }
        // exchange halves within the pair -> both lanes hold the full z row
#pragma unroll
        for (int j = 0; j < 20; ++j) z[j] += __shfl_xor(z[j], 1, 64);
    }
    // BN2 partial stats (each row counted twice across the pair -> 0.5 at write)
    {
        float s_[20], q_[20];
#pragma unroll
        for (int j = 0; j < 20; ++j) { s_[j] = z[j]; q_[j] = z[j] * z[j]; }
#pragma unroll
        for (int off = 32; off >= 1; off >>= 1) {
#pragma unroll
            for (int j = 0; j < 20; ++j) {
                s_[j] += __shfl_down(s_[j], off, 64);
                q_[j] += __shfl_down(q_[j], off, 64);
            }
        }
        const int wave = t >> 6, lane = t & 63;
        if (lane == 0) {
#pragma unroll
            for (int j = 0; j < 20; ++j) {
                sRed[wave][j] = s_[j];
                sRed[wave][20 + j] = q_[j];
            }
        }
        __syncthreads();
        if (t < 40)
            part2t[(size_t)t * CB + b] =
                0.5f * (sRed[0][t] + sRed[1][t] + sRed[2][t] + sRed[3][t]);
    }
    __threadfence();
    grid.sync();

    // ---------------- R2: reduce BN2 partials ----------------
    if (b < 40) {
        float val = 0.0f;
#pragma unroll
        for (int p = t; p < CB; p += 256) val += part2t[(size_t)b * CB + p];
#pragma unroll
        for (int off = 32; off >= 1; off >>= 1) val += __shfl_down(val, off, 64);
        if ((t & 63) == 0) sT[t >> 6] = val;
        __syncthreads();
        if (t == 0) bn2s[b] = sT[0] + sT[1] + sT[2] + sT[3];
    }
    __threadfence();
    grid.sync();

    // ---------------- phase C: BN2 + GELU + split fuzzy + head ----------------
    if (t < 40) sT[t] = bn2s[t];
    __syncthreads();
    if (t < 20) {
        float mu = sT[t] * (1.0f / B_N);
        float var = fmaxf(sT[20 + t] * (1.0f / B_N) - mu * mu, 0.0f);
        float sc = g2[t] * rsqrtf(var + 1e-5f);
        sSc[t] = sc;
        sSh[t] = b2[t] - mu * sc;
    }
    __syncthreads();
#pragma unroll
    for (int j = 0; j < 20; ++j)
        z[j] = gelu_exact(sSc[j] * z[j] + sSh[j]);
    float acc = half ? 0.0f : hb[0];
#pragma unroll 1
    for (int rr = 0; rr < 5; ++rr) {
        const int r = half * 5 + rr;
        float u = 0.0f, l = 0.0f;
#pragma unroll
        for (int j = 0; j < 20; ++j) {
            float4 p = sFz[r * 20 + j];
            float d = z[j] - p.x;
            float dd = d * d;
            u += __expf(dd * p.y);
            l += __expf(dd * p.z);
        }
        acc += sHW[r] * 0.025f * (u + l);
    }
    acc += __shfl_xor(acc, 1, 64);
    if (!half) out[pair] = acc;
}

// ======================= fallback pipeline (round-2, known good) =======================
__global__ __launch_bounds__(256) void k_act_moments(
    const float* __restrict__ x, const float* __restrict__ cen,
    const float* __restrict__ lw, const float* __restrict__ rw,
    const float* __restrict__ linw, float* __restrict__ stat1)
{
    __shared__ float sAcc[4][8][44];
    const int t = threadIdx.x;
    const int g = t & 7;
    const int rl = t >> 3;
    float c_[8], nh_[8], w_[8];
#pragma unroll
    for (int k = 0; k < 8; ++k) {
        c_[k] = cen[g * 8 + k];
        float s = expf(lw[g * 8 + k]) + 1e-6f;
        nh_[k] = -0.5f / (s * s);
        w_[k] = rw[g * 8 + k];
    }
    const float lin = linw[g];
    float sumA[8], P[36];
#pragma unroll
    for (int f = 0; f < 8; ++f) sumA[f] = 0.0f;
#pragma unroll
    for (int i = 0; i < 36; ++i) P[i] = 0.0f;
    for (int row = blockIdx.x * 32 + rl; row < B_N; row += gridDim.x * 32) {
        const float* xr = x + (size_t)row * 64 + g * 8;
        float4 v0 = *(const float4*)(xr);
        float4 v1 = *(const float4*)(xr + 4);
        float xv[8] = {v0.x, v0.y, v0.z, v0.w, v1.x, v1.y, v1.z, v1.w};
        float act[8];
#pragma unroll
        for (int f = 0; f < 8; ++f) {
            float v = xv[f];
            float a = lin * v;
#pragma unroll
            for (int k = 0; k < 8; ++k) {
                float d = v - c_[k];
                a += w_[k] * __expf(d * d * nh_[k]);
            }
            act[f] = a;
        }
        int idx = 0;
#pragma unroll
        for (int f = 0; f < 8; ++f) {
            sumA[f] += act[f];
#pragma unroll
            for (int f2 = 0; f2 <= f; ++f2) { P[idx] += act[f] * act[f2]; ++idx; }
        }
    }
#pragma unroll
    for (int off = 32; off >= 8; off >>= 1) {
#pragma unroll
        for (int f = 0; f < 8; ++f) sumA[f] += __shfl_down(sumA[f], off, 64);
#pragma unroll
        for (int i = 0; i < 36; ++i) P[i] += __shfl_down(P[i], off, 64);
    }
    const int wave = t >> 6, lane = t & 63;
    if (lane < 8) {
        float* dst = &sAcc[wave][lane][0];
#pragma unroll
        for (int f = 0; f < 8; ++f) dst[f] = sumA[f];
#pragma unroll
        for (int i = 0; i < 36; ++i) dst[8 + i] = P[i];
    }
    __syncthreads();
    for (int i = t; i < 352; i += 256) {
        int gg = i / 44, v = i % 44;
        float s = sAcc[0][gg][v] + sAcc[1][gg][v] + sAcc[2][gg][v] + sAcc[3][gg][v];
        atomicAdd(&stat1[(blockIdx.x & 63) * 352 + i], s);
    }
}

__global__ __launch_bounds__(256) void k_build(
    const float* __restrict__ stat1, const float* __restrict__ fpW,
    const float* __restrict__ fpb, const float* __restrict__ g1,
    const float* __restrict__ b1, const float* __restrict__ Wp,
    const float* __restrict__ pb, const float* __restrict__ lsu,
    const float* __restrict__ lsl,
    float* __restrict__ Mt, float* __restrict__ Cc, float* __restrict__ nh,
    float* __restrict__ stat2)
{
    __shared__ float Am[8][8];
    __shared__ float Sg[8][36];
    __shared__ float a_[128], bb_[128];
    const int t = threadIdx.x;
    for (int i = t; i < 352; i += 256) {
        float s = 0.0f;
        for (int st = 0; st < 64; ++st) s += stat1[st * 352 + i];
        float m = s * (1.0f / B_N);
        int g = i / 44, v = i % 44;
        if (v < 8) Am[g][v] = m; else Sg[g][v - 8] = m;
    }
    __syncthreads();
    if (t < 128) {
        const int g = t >> 4;
        float wv[8];
#pragma unroll
        for (int f = 0; f < 8; ++f) wv[f] = Wp[t * 8 + f];
        float dot = 0.0f;
#pragma unroll
        for (int f = 0; f < 8; ++f) dot += wv[f] * Am[g][f];
        const float pbv = pb[t];
        const float mu = pbv + dot;
        float e2 = pbv * pbv + 2.0f * pbv * dot;
        int idx = 0;
#pragma unroll
        for (int f = 0; f < 8; ++f)
#pragma unroll
            for (int f2 = 0; f2 <= f; ++f2) {
                float c2 = (f2 == f) ? 1.0f : 2.0f;
                e2 += c2 * wv[f] * wv[f2] * Sg[g][idx]; ++idx;
            }
        const float var = fmaxf(e2 - mu * mu, 0.0f);
        const float a = g1[t] * rsqrtf(var + 1e-5f);
        a_[t] = a;
        bb_[t] = b1[t] - mu * a;
    }
    __syncthreads();
    for (int i = t; i < 1280; i += 256) {
        int gf = i / 20, j = i % 20;
        int g = gf >> 3, f = gf & 7;
        float m = 0.0f;
        for (int o = 0; o < 16; ++o) {
            int c = g * 16 + o;
            m += fpW[j * 128 + c] * a_[c] * Wp[c * 8 + f];
        }
        Mt[i] = m;
    }
    if (t < 20) {
        float cj = fpb[t];
        for (int c = 0; c < 128; ++c)
            cj += fpW[t * 128 + c] * (a_[c] * pb[c] + bb_[c]);
        Cc[t] = cj;
    }
    for (int i = t; i < 200; i += 256) {
        float su = expf(lsu[i]) + 1e-6f;
        float sl = fminf(expf(lsl[i]) + 1e-6f, 0.9f * su);
        nh[i] = -0.5f / (su * su);
        nh[200 + i] = -0.5f / (sl * sl);
    }
    for (int i = t; i < 2560; i += 256) stat2[i] = 0.0f;
}

__device__ __forceinline__ void zpre_row(
    const float* __restrict__ xr, const float4* __restrict__ sRbf,
    const float* __restrict__ sLin, const float* __restrict__ sMt,
    const float* __restrict__ sC, float zp[20])
{
#pragma unroll
    for (int j = 0; j < 20; ++j) zp[j] = sC[j];
#pragma unroll 1
    for (int g = 0; g < 8; ++g) {
        float4 v0 = *(const float4*)(xr + g * 8);
        float4 v1 = *(const float4*)(xr + g * 8 + 4);
        float xv[8] = {v0.x, v0.y, v0.z, v0.w, v1.x, v1.y, v1.z, v1.w};
        float act[8];
        float lin = sLin[g];
#pragma unroll
        for (int f = 0; f < 8; ++f) act[f] = lin * xv[f];
#pragma unroll 1
        for (int k = 0; k < 8; ++k) {
            float4 p = sRbf[g * 8 + k];
#pragma unroll
            for (int f = 0; f < 8; ++f) {
                float d = xv[f] - p.x;
                act[f] += p.y * __expf(d * d * p.z);
            }
        }
#pragma unroll 1
        for (int f = 0; f < 8; ++f) {
            float av = act[f];
            const float4* m4 = (const float4*)(sMt + (g * 8 + f) * 20);
            float4 ma = m4[0], mb = m4[1], mc = m4[2], md = m4[3], me = m4[4];
            zp[0] += av * ma.x; zp[1] += av * ma.y; zp[2] += av * ma.z; zp[3] += av * ma.w;
            zp[4] += av * mb.x; zp[5] += av * mb.y; zp[6] += av * mb.z; zp[7] += av * mb.w;
            zp[8] += av * mc.x; zp[9] += av * mc.y; zp[10] += av * mc.z; zp[11] += av * mc.w;
            zp[12] += av * md.x; zp[13] += av * md.y; zp[14] += av * md.z; zp[15] += av * md.w;
            zp[16] += av * me.x; zp[17] += av * me.y; zp[18] += av * me.z; zp[19] += av * me.w;
        }
    }
}

__global__ __launch_bounds__(256) void k_zpre_stats(
    const float* __restrict__ x, const float* __restrict__ cen,
    const float* __restrict__ lw, const float* __restrict__ rw,
    const float* __restrict__ linw, const float* __restrict__ Mt,
    const float* __restrict__ Cc, float* __restrict__ zout,
    float* __restrict__ stat2)
{
    __shared__ __align__(16) float4 sRbf[64];
    __shared__ float sLin[8], sC[20];
    __shared__ __align__(16) float sMt[1280];
    __shared__ float sRed[4][40];
    const int t = threadIdx.x;
    if (t < 64) {
        float s = expf(lw[t]) + 1e-6f;
        sRbf[t] = make_float4(cen[t], rw[t], -0.5f / (s * s), 0.0f);
    }
    if (t < 8)  sLin[t] = linw[t];
    if (t < 20) sC[t] = Cc[t];
    for (int i = t; i < 1280; i += 256) sMt[i] = Mt[i];
    __syncthreads();
    const int row = blockIdx.x * 256 + t;
    float zp[20];
    zpre_row(x + (size_t)row * 64, sRbf, sLin, sMt, sC, zp);
#pragma unroll
    for (int j = 0; j < 20; ++j) zout[(size_t)j * B_N + row] = zp[j];
    float s_[20], q_[20];
#pragma unroll
    for (int j = 0; j < 20; ++j) { s_[j] = zp[j]; q_[j] = zp[j] * zp[j]; }
#pragma unroll
    for (int off = 32; off >= 1; off >>= 1) {
#pragma unroll
        for (int j = 0; j < 20; ++j) {
            s_[j] += __shfl_down(s_[j], off, 64);
            q_[j] += __shfl_down(q_[j], off, 64);
        }
    }
    const int wave = t >> 6, lane = t & 63;
    if (lane == 0) {
#pragma unroll
        for (int j = 0; j < 20; ++j) { sRed[wave][j] = s_[j]; sRed[wave][20 + j] = q_[j]; }
    }
    __syncthreads();
    if (t < 40) {
        float v = sRed[0][t] + sRed[1][t] + sRed[2][t] + sRed[3][t];
        atomicAdd(&stat2[(blockIdx.x & 63) * 40 + t], v);
    }
}

__global__ __launch_bounds__(256) void k_out2(
    const float* __restrict__ zin, const float* __restrict__ stat2,
    const float* __restrict__ g2, const float* __restrict__ b2,
    const float* __restrict__ nh, const float* __restrict__ fzc,
    const float* __restrict__ hW, const float* __restrict__ hb,
    float* __restrict__ out)
{
    __shared__ float sT[40], sSc[20], sSh[20], sHW[10];
    __shared__ __align__(16) float4 sFz[200];
    const int t = threadIdx.x;
    if (t < 10) sHW[t] = hW[t];
    for (int i = t; i < 200; i += 256)
        sFz[i] = make_float4(fzc[i], nh[i], nh[200 + i], 0.0f);
    if (t < 40) {
        float s = 0.0f;
        for (int st = 0; st < 64; ++st) s += stat2[st * 40 + t];
        sT[t] = s;
    }
    __syncthreads();
    if (t < 20) {
        float mu = sT[t] * (1.0f / B_N);
        float var = fmaxf(sT[20 + t] * (1.0f / B_N) - mu * mu, 0.0f);
        float sc = g2[t] * rsqrtf(var + 1e-5f);
        sSc[t] = sc;
        sSh[t] = b2[t] - mu * sc;
    }
    __syncthreads();
    const int r0 = (blockIdx.x * 256 + t) * 2;
    float z0[20], z1[20];
#pragma unroll
    for (int j = 0; j < 20; ++j) {
        float2 v = *(const float2*)(zin + (size_t)j * B_N + r0);
        z0[j] = gelu_exact(sSc[j] * v.x + sSh[j]);
        z1[j] = gelu_exact(sSc[j] * v.y + sSh[j]);
    }
    const float hbv = hb[0];
    float acc0 = hbv, acc1 = hbv;
#pragma unroll 1
    for (int r = 0; r < 10; ++r) {
        float u0 = 0.0f, l0 = 0.0f, u1 = 0.0f, l1 = 0.0f;
#pragma unroll
        for (int j = 0; j < 20; ++j) {
            float4 p = sFz[r * 20 + j];
            float d0 = z0[j] - p.x, d1 = z1[j] - p.x;
            float dd0 = d0 * d0, dd1 = d1 * d1;
            u0 += __expf(dd0 * p.y); l0 += __expf(dd0 * p.z);
            u1 += __expf(dd1 * p.y); l1 += __expf(dd1 * p.z);
        }
        float w = sHW[r] * 0.025f;
        acc0 += w * (u0 + l0);
        acc1 += w * (u1 + l1);
    }
    *(float2*)(out + r0) = make_float2(acc0, acc1);
}

// ---------------- launcher ----------------
extern "C" void kernel_launch(void* const* d_in, const int* in_sizes, int n_in,
                              void* d_out, int out_size, void* d_ws, size_t ws_size,
                              hipStream_t stream) {
    const float* x    = (const float*)d_in[0];
    const float* cen  = (const float*)d_in[1];
    const float* lw   = (const float*)d_in[2];
    const float* rw   = (const float*)d_in[3];
    const float* linw = (const float*)d_in[4];
    const float* Wp   = (const float*)d_in[5];
    const float* pb   = (const float*)d_in[6];
    const float* g1   = (const float*)d_in[7];
    const float* b1   = (const float*)d_in[8];
    const float* fpW  = (const float*)d_in[9];
    const float* fpb  = (const float*)d_in[10];
    const float* g2   = (const float*)d_in[11];
    const float* b2   = (const float*)d_in[12];
    const float* fzc  = (const float*)d_in[13];
    const float* lsu  = (const float*)d_in[14];
    const float* lsl  = (const float*)d_in[15];
    const float* hW   = (const float*)d_in[16];
    const float* hb   = (const float*)d_in[17];

    float* wsf  = (float*)d_ws;
    float* outp = (float*)d_out;

    // ---- cooperative path: require 4 blocks/CU co-residency ----
    int maxb = 0;
    hipError_t qe = hipOccupancyMaxActiveBlocksPerMultiprocessor(&maxb, k_fused, CT, 0);
    if (qe == hipSuccess && maxb >= 4) {
        void* args[20] = {
            (void*)&x, (void*)&cen, (void*)&lw, (void*)&rw, (void*)&linw,
            (void*)&Wp, (void*)&pb, (void*)&g1, (void*)&b1, (void*)&fpW,
            (void*)&fpb, (void*)&g2, (void*)&b2, (void*)&fzc, (void*)&lsu,
            (void*)&lsl, (void*)&hW, (void*)&hb, (void*)&wsf, (void*)&outp
        };
        hipError_t e = hipLaunchCooperativeKernel((const void*)k_fused,
                                                  dim3(CB), dim3(CT), args, 0, stream);
        if (e == hipSuccess) return;
        (void)hipGetLastError();   // clear sticky error, fall back
    } else {
        (void)hipGetLastError();
    }

    // ---- fallback: 5-dispatch pipeline (round-2 structure) ----
    float* stat1 = wsf + WS_STAT1;
    float* Mt    = wsf + WS_MT;
    float* Cc    = wsf + WS_C;
    float* stat2 = wsf + WS_STAT2;
    float* nh    = wsf + WS_NH;
    float* zbuf  = wsf + WS_Z2;

    hipMemsetAsync(stat1, 0, (size_t)ST1_SZ * sizeof(float), stream);
    k_act_moments<<<1024, 256, 0, stream>>>(x, cen, lw, rw, linw, stat1);
    k_build<<<1, 256, 0, stream>>>(stat1, fpW, fpb, g1, b1, Wp, pb, lsu, lsl,
                                   Mt, Cc, nh, stat2);
    k_zpre_stats<<<512, 256, 0, stream>>>(x, cen, lw, rw, linw, Mt, Cc, zbuf, stat2);
    k_out2<<<256, 256, 0, stream>>>(zbuf, stat2, g2, b2, nh, fzc, hW, hb, outp);
}

// Round 7
// 179.557 us; speedup vs baseline: 2.1609x; 1.0363x over previous
//
#include <hip/hip_runtime.h>
#include <hip/hip_fp16.h>
#include <math.h>

#define B_N 131072

// ---------------- ws layout (float offsets) ----------------
#define WS_STAT1 0
#define ST1_SZ   (64 * 352)          // 22528
#define WS_MT    22528               // Mt[64][20]
#define WS_C     23808               // C[20]
#define WS_STAT2 23840               // 64 stripes x 40 -> 26400
#define WS_NH    26400               // nhu[200], nhl[200] -> 26800
#define WS_ACTH  26816               // act fp16 [B][64]  (B*32 floats of storage)
#define WS_Z     (26816 + (size_t)B_N * 32)   // z col-major [20][B]
#define WS_END   (WS_Z + (size_t)B_N * 20)

struct alignas(16) H8 { __half2 a, b, c, d; };

__device__ __forceinline__ float gelu_exact(float v) {
    return 0.5f * v * (1.0f + erff(v * 0.70710678118654752440f));
}

// ---------------- pass 1: RBF -> act (fp16 store) + act moments ----------------
__global__ __launch_bounds__(256) void k_act_moments(
    const float* __restrict__ x, const float* __restrict__ cen,
    const float* __restrict__ lw, const float* __restrict__ rw,
    const float* __restrict__ linw, __half* __restrict__ act_h,
    float* __restrict__ stat1, int store)
{
    __shared__ float sAcc[4][8][44];
    const int t = threadIdx.x;
    const int g = t & 7;
    const int rl = t >> 3;

    float c_[8], nh_[8], w_[8];
#pragma unroll
    for (int k = 0; k < 8; ++k) {
        c_[k] = cen[g * 8 + k];
        float s = expf(lw[g * 8 + k]) + 1e-6f;
        nh_[k] = -0.5f / (s * s);
        w_[k] = rw[g * 8 + k];
    }
    const float lin = linw[g];

    float sumA[8], P[36];
#pragma unroll
    for (int f = 0; f < 8; ++f) sumA[f] = 0.0f;
#pragma unroll
    for (int i = 0; i < 36; ++i) P[i] = 0.0f;

#pragma unroll 1
    for (int row = blockIdx.x * 32 + rl; row < B_N; row += gridDim.x * 32) {
        const float* xr = x + (size_t)row * 64 + g * 8;
        float4 v0 = *(const float4*)(xr);
        float4 v1 = *(const float4*)(xr + 4);
        float xv[8] = {v0.x, v0.y, v0.z, v0.w, v1.x, v1.y, v1.z, v1.w};
        float act[8];
#pragma unroll
        for (int f = 0; f < 8; ++f) {
            float v = xv[f];
            float a = lin * v;
#pragma unroll
            for (int k = 0; k < 8; ++k) {
                float d = v - c_[k];
                a += w_[k] * __expf(d * d * nh_[k]);
            }
            act[f] = a;
        }
        if (store) {
            H8 h;
            h.a = __floats2half2_rn(act[0], act[1]);
            h.b = __floats2half2_rn(act[2], act[3]);
            h.c = __floats2half2_rn(act[4], act[5]);
            h.d = __floats2half2_rn(act[6], act[7]);
            *(H8*)(act_h + (size_t)row * 64 + g * 8) = h;
        }
        int idx = 0;
#pragma unroll
        for (int f = 0; f < 8; ++f) {
            sumA[f] += act[f];
#pragma unroll
            for (int f2 = 0; f2 <= f; ++f2) { P[idx] += act[f] * act[f2]; ++idx; }
        }
    }

#pragma unroll
    for (int off = 32; off >= 8; off >>= 1) {
#pragma unroll
        for (int f = 0; f < 8; ++f) sumA[f] += __shfl_down(sumA[f], off, 64);
#pragma unroll
        for (int i = 0; i < 36; ++i) P[i] += __shfl_down(P[i], off, 64);
    }
    const int wave = t >> 6, lane = t & 63;
    if (lane < 8) {   // lane == g
        float* dst = &sAcc[wave][lane][0];
#pragma unroll
        for (int f = 0; f < 8; ++f) dst[f] = sumA[f];
#pragma unroll
        for (int i = 0; i < 36; ++i) dst[8 + i] = P[i];
    }
    __syncthreads();
    for (int i = t; i < 352; i += 256) {
        int gg = i / 44, v = i % 44;
        float s = sAcc[0][gg][v] + sAcc[1][gg][v] + sAcc[2][gg][v] + sAcc[3][gg][v];
        atomicAdd(&stat1[(blockIdx.x & 63) * 352 + i], s);
    }
}

// ---------------- build: BN1 fold -> Mt/C, fuzzy tables, zero stat2 ----------------
__global__ __launch_bounds__(256) void k_build(
    const float* __restrict__ stat1, const float* __restrict__ fpW,
    const float* __restrict__ fpb, const float* __restrict__ g1,
    const float* __restrict__ b1, const float* __restrict__ Wp,
    const float* __restrict__ pb, const float* __restrict__ lsu,
    const float* __restrict__ lsl,
    float* __restrict__ Mt, float* __restrict__ Cc, float* __restrict__ nh,
    float* __restrict__ stat2)
{
    __shared__ float Am[8][8];
    __shared__ float Sg[8][36];
    __shared__ float a_[128], bb_[128];
    const int t = threadIdx.x;
    for (int i = t; i < 352; i += 256) {
        float s = 0.0f;
        for (int st = 0; st < 64; ++st) s += stat1[st * 352 + i];
        float m = s * (1.0f / B_N);
        int g = i / 44, v = i % 44;
        if (v < 8) Am[g][v] = m; else Sg[g][v - 8] = m;
    }
    __syncthreads();
    if (t < 128) {
        const int g = t >> 4;
        float wv[8];
#pragma unroll
        for (int f = 0; f < 8; ++f) wv[f] = Wp[t * 8 + f];
        float dot = 0.0f;
#pragma unroll
        for (int f = 0; f < 8; ++f) dot += wv[f] * Am[g][f];
        const float pbv = pb[t];
        const float mu = pbv + dot;
        float e2 = pbv * pbv + 2.0f * pbv * dot;
        int idx = 0;
#pragma unroll
        for (int f = 0; f < 8; ++f)
#pragma unroll
            for (int f2 = 0; f2 <= f; ++f2) {
                float c2 = (f2 == f) ? 1.0f : 2.0f;
                e2 += c2 * wv[f] * wv[f2] * Sg[g][idx]; ++idx;
            }
        const float var = fmaxf(e2 - mu * mu, 0.0f);
        const float a = g1[t] * rsqrtf(var + 1e-5f);
        a_[t] = a;
        bb_[t] = b1[t] - mu * a;
    }
    __syncthreads();
    for (int i = t; i < 1280; i += 256) {
        int gf = i / 20, j = i % 20;
        int g = gf >> 3, f = gf & 7;
        float m = 0.0f;
        for (int o = 0; o < 16; ++o) {
            int c = g * 16 + o;
            m += fpW[j * 128 + c] * a_[c] * Wp[c * 8 + f];
        }
        Mt[i] = m;
    }
    if (t < 20) {
        float cj = fpb[t];
        for (int c = 0; c < 128; ++c)
            cj += fpW[t * 128 + c] * (a_[c] * pb[c] + bb_[c]);
        Cc[t] = cj;
    }
    for (int i = t; i < 200; i += 256) {
        float su = expf(lsu[i]) + 1e-6f;
        float sl = fminf(expf(lsl[i]) + 1e-6f, 0.9f * su);
        nh[i] = -0.5f / (su * su);
        nh[200 + i] = -0.5f / (sl * sl);
    }
    for (int i = t; i < 2560; i += 256) stat2[i] = 0.0f;
}

// ---------------- pass 2: z = act_h · Mt + C (exp-free), BN2 stats ----------------
// 256 blocks x 128 threads x 4 rows/thread
__global__ __launch_bounds__(128) void k_z(
    const __half* __restrict__ act_h, const float* __restrict__ Mt,
    const float* __restrict__ Cc, float* __restrict__ zout,
    float* __restrict__ stat2)
{
    __shared__ __align__(16) float sMt[1280];
    __shared__ float sC[20];
    __shared__ float sRed[2][40];

    const int t = threadIdx.x;
    for (int i = t; i < 1280; i += 128) sMt[i] = Mt[i];
    if (t < 20) sC[t] = Cc[t];
    __syncthreads();

    const int r0 = (blockIdx.x * 128 + t) * 4;
    float zp[4][20];
#pragma unroll
    for (int r = 0; r < 4; ++r)
#pragma unroll
        for (int j = 0; j < 20; ++j) zp[r][j] = sC[j];

#pragma unroll 1
    for (int g = 0; g < 8; ++g) {
        float a[4][8];
#pragma unroll
        for (int r = 0; r < 4; ++r) {
            const H8 h = *(const H8*)(act_h + (size_t)(r0 + r) * 64 + g * 8);
            float2 f0 = __half22float2(h.a), f1 = __half22float2(h.b);
            float2 f2 = __half22float2(h.c), f3 = __half22float2(h.d);
            a[r][0] = f0.x; a[r][1] = f0.y; a[r][2] = f1.x; a[r][3] = f1.y;
            a[r][4] = f2.x; a[r][5] = f2.y; a[r][6] = f3.x; a[r][7] = f3.y;
        }
#pragma unroll
        for (int f = 0; f < 8; ++f) {
            const float4* m4 = (const float4*)(sMt + (g * 8 + f) * 20);
            float4 ma = m4[0], mb = m4[1], mc = m4[2], md = m4[3], me = m4[4];
#pragma unroll
            for (int r = 0; r < 4; ++r) {
                float av = a[r][f];
                zp[r][0] += av * ma.x; zp[r][1] += av * ma.y; zp[r][2] += av * ma.z; zp[r][3] += av * ma.w;
                zp[r][4] += av * mb.x; zp[r][5] += av * mb.y; zp[r][6] += av * mb.z; zp[r][7] += av * mb.w;
                zp[r][8] += av * mc.x; zp[r][9] += av * mc.y; zp[r][10] += av * mc.z; zp[r][11] += av * mc.w;
                zp[r][12] += av * md.x; zp[r][13] += av * md.y; zp[r][14] += av * md.z; zp[r][15] += av * md.w;
                zp[r][16] += av * me.x; zp[r][17] += av * me.y; zp[r][18] += av * me.z; zp[r][19] += av * me.w;
            }
        }
    }

    // coalesced col-major store
#pragma unroll
    for (int j = 0; j < 20; ++j) {
        *(float4*)(zout + (size_t)j * B_N + r0) =
            make_float4(zp[0][j], zp[1][j], zp[2][j], zp[3][j]);
    }

    // BN2 partial stats
    float s_[20], q_[20];
#pragma unroll
    for (int j = 0; j < 20; ++j) {
        s_[j] = zp[0][j] + zp[1][j] + zp[2][j] + zp[3][j];
        q_[j] = zp[0][j]*zp[0][j] + zp[1][j]*zp[1][j] + zp[2][j]*zp[2][j] + zp[3][j]*zp[3][j];
    }
#pragma unroll
    for (int off = 32; off >= 1; off >>= 1) {
#pragma unroll
        for (int j = 0; j < 20; ++j) {
            s_[j] += __shfl_down(s_[j], off, 64);
            q_[j] += __shfl_down(q_[j], off, 64);
        }
    }
    const int wave = t >> 6, lane = t & 63;
    if (lane == 0) {
#pragma unroll
        for (int j = 0; j < 20; ++j) { sRed[wave][j] = s_[j]; sRed[wave][20 + j] = q_[j]; }
    }
    __syncthreads();
    if (t < 40) {
        float v = sRed[0][t] + sRed[1][t];
        atomicAdd(&stat2[(blockIdx.x & 63) * 40 + t], v);
    }
}

// ---------------- fallback pass 2 (ws too small): recompute RBF ----------------
__global__ __launch_bounds__(256) void k_zpre_stats(
    const float* __restrict__ x, const float* __restrict__ cen,
    const float* __restrict__ lw, const float* __restrict__ rw,
    const float* __restrict__ linw, const float* __restrict__ Mt,
    const float* __restrict__ Cc, float* __restrict__ zout,
    float* __restrict__ stat2)
{
    __shared__ __align__(16) float4 sRbf[64];
    __shared__ float sLin[8], sC[20];
    __shared__ __align__(16) float sMt[1280];
    __shared__ float sRed[4][40];
    const int t = threadIdx.x;
    if (t < 64) {
        float s = expf(lw[t]) + 1e-6f;
        sRbf[t] = make_float4(cen[t], rw[t], -0.5f / (s * s), 0.0f);
    }
    if (t < 8)  sLin[t] = linw[t];
    if (t < 20) sC[t] = Cc[t];
    for (int i = t; i < 1280; i += 256) sMt[i] = Mt[i];
    __syncthreads();
    const int row = blockIdx.x * 256 + t;
    const float* xr = x + (size_t)row * 64;
    float zp[20];
#pragma unroll
    for (int j = 0; j < 20; ++j) zp[j] = sC[j];
#pragma unroll 1
    for (int g = 0; g < 8; ++g) {
        float4 v0 = *(const float4*)(xr + g * 8);
        float4 v1 = *(const float4*)(xr + g * 8 + 4);
        float xv[8] = {v0.x, v0.y, v0.z, v0.w, v1.x, v1.y, v1.z, v1.w};
        float act[8];
        float lin = sLin[g];
#pragma unroll
        for (int f = 0; f < 8; ++f) act[f] = lin * xv[f];
#pragma unroll 1
        for (int k = 0; k < 8; ++k) {
            float4 p = sRbf[g * 8 + k];
#pragma unroll
            for (int f = 0; f < 8; ++f) {
                float d = xv[f] - p.x;
                act[f] += p.y * __expf(d * d * p.z);
            }
        }
#pragma unroll 1
        for (int f = 0; f < 8; ++f) {
            float av = act[f];
            const float4* m4 = (const float4*)(sMt + (g * 8 + f) * 20);
            float4 ma = m4[0], mb = m4[1], mc = m4[2], md = m4[3], me = m4[4];
            zp[0] += av * ma.x; zp[1] += av * ma.y; zp[2] += av * ma.z; zp[3] += av * ma.w;
            zp[4] += av * mb.x; zp[5] += av * mb.y; zp[6] += av * mb.z; zp[7] += av * mb.w;
            zp[8] += av * mc.x; zp[9] += av * mc.y; zp[10] += av * mc.z; zp[11] += av * mc.w;
            zp[12] += av * md.x; zp[13] += av * md.y; zp[14] += av * md.z; zp[15] += av * md.w;
            zp[16] += av * me.x; zp[17] += av * me.y; zp[18] += av * me.z; zp[19] += av * me.w;
        }
    }
#pragma unroll
    for (int j = 0; j < 20; ++j) zout[(size_t)j * B_N + row] = zp[j];
    float s_[20], q_[20];
#pragma unroll
    for (int j = 0; j < 20; ++j) { s_[j] = zp[j]; q_[j] = zp[j] * zp[j]; }
#pragma unroll
    for (int off = 32; off >= 1; off >>= 1) {
#pragma unroll
        for (int j = 0; j < 20; ++j) {
            s_[j] += __shfl_down(s_[j], off, 64);
            q_[j] += __shfl_down(q_[j], off, 64);
        }
    }
    const int wave = t >> 6, lane = t & 63;
    if (lane == 0) {
#pragma unroll
        for (int j = 0; j < 20; ++j) { sRed[wave][j] = s_[j]; sRed[wave][20 + j] = q_[j]; }
    }
    __syncthreads();
    if (t < 40) {
        float v = sRed[0][t] + sRed[1][t] + sRed[2][t] + sRed[3][t];
        atomicAdd(&stat2[(blockIdx.x & 63) * 40 + t], v);
    }
}

// ---------------- pass 3: BN2 + GELU + fuzzy + head (2 rows/thread) ----------------
__global__ __launch_bounds__(256) void k_out2(
    const float* __restrict__ zin, const float* __restrict__ stat2,
    const float* __restrict__ g2, const float* __restrict__ b2,
    const float* __restrict__ nh, const float* __restrict__ fzc,
    const float* __restrict__ hW, const float* __restrict__ hb,
    float* __restrict__ out)
{
    __shared__ float sT[40], sSc[20], sSh[20], sHW[10];
    __shared__ __align__(16) float4 sFz[200];
    const int t = threadIdx.x;
    if (t < 10) sHW[t] = hW[t];
    for (int i = t; i < 200; i += 256)
        sFz[i] = make_float4(fzc[i], nh[i], nh[200 + i], 0.0f);
    if (t < 40) {
        float s = 0.0f;
        for (int st = 0; st < 64; ++st) s += stat2[st * 40 + t];
        sT[t] = s;
    }
    __syncthreads();
    if (t < 20) {
        float mu = sT[t] * (1.0f / B_N);
        float var = fmaxf(sT[20 + t] * (1.0f / B_N) - mu * mu, 0.0f);
        float sc = g2[t] * rsqrtf(var + 1e-5f);
        sSc[t] = sc;
        sSh[t] = b2[t] - mu * sc;
    }
    __syncthreads();
    const int r0 = (blockIdx.x * 256 + t) * 2;
    float z0[20], z1[20];
#pragma unroll
    for (int j = 0; j < 20; ++j) {
        float2 v = *(const float2*)(zin + (size_t)j * B_N + r0);
        z0[j] = gelu_exact(sSc[j] * v.x + sSh[j]);
        z1[j] = gelu_exact(sSc[j] * v.y + sSh[j]);
    }
    const float hbv = hb[0];
    float acc0 = hbv, acc1 = hbv;
#pragma unroll 1
    for (int r = 0; r < 10; ++r) {
        float u0 = 0.0f, l0 = 0.0f, u1 = 0.0f, l1 = 0.0f;
#pragma unroll
        for (int j = 0; j < 20; ++j) {
            float4 p = sFz[r * 20 + j];
            float d0 = z0[j] - p.x, d1 = z1[j] - p.x;
            float dd0 = d0 * d0, dd1 = d1 * d1;
            u0 += __expf(dd0 * p.y); l0 += __expf(dd0 * p.z);
            u1 += __expf(dd1 * p.y); l1 += __expf(dd1 * p.z);
        }
        float w = sHW[r] * 0.025f;
        acc0 += w * (u0 + l0);
        acc1 += w * (u1 + l1);
    }
    *(float2*)(out + r0) = make_float2(acc0, acc1);
}

// ---------------- launcher ----------------
extern "C" void kernel_launch(void* const* d_in, const int* in_sizes, int n_in,
                              void* d_out, int out_size, void* d_ws, size_t ws_size,
                              hipStream_t stream) {
    const float* x    = (const float*)d_in[0];
    const float* cen  = (const float*)d_in[1];
    const float* lw   = (const float*)d_in[2];
    const float* rw   = (const float*)d_in[3];
    const float* linw = (const float*)d_in[4];
    const float* Wp   = (const float*)d_in[5];
    const float* pb   = (const float*)d_in[6];
    const float* g1   = (const float*)d_in[7];
    const float* b1   = (const float*)d_in[8];
    const float* fpW  = (const float*)d_in[9];
    const float* fpb  = (const float*)d_in[10];
    const float* g2   = (const float*)d_in[11];
    const float* b2   = (const float*)d_in[12];
    const float* fzc  = (const float*)d_in[13];
    const float* lsu  = (const float*)d_in[14];
    const float* lsl  = (const float*)d_in[15];
    const float* hW   = (const float*)d_in[16];
    const float* hb   = (const float*)d_in[17];

    float* ws    = (float*)d_ws;
    float* stat1 = ws + WS_STAT1;
    float* Mt    = ws + WS_MT;
    float* Cc    = ws + WS_C;
    float* stat2 = ws + WS_STAT2;
    float* nh    = ws + WS_NH;
    __half* acth = (__half*)(ws + WS_ACTH);
    float* zbuf  = ws + WS_Z;
    float* outp  = (float*)d_out;

    const size_t needFull = WS_END * sizeof(float);
    const size_t needZ    = ((size_t)WS_ACTH + (size_t)20 * B_N) * sizeof(float);
    const int mode = (ws_size >= needFull) ? 2 : (ws_size >= needZ ? 1 : 1);
    if (mode == 1) zbuf = ws + WS_ACTH;   // no act buffer in fallback mode

    hipMemsetAsync(stat1, 0, (size_t)ST1_SZ * sizeof(float), stream);
    k_act_moments<<<1024, 256, 0, stream>>>(x, cen, lw, rw, linw, acth, stat1,
                                            mode == 2 ? 1 : 0);
    k_build<<<1, 256, 0, stream>>>(stat1, fpW, fpb, g1, b1, Wp, pb, lsu, lsl,
                                   Mt, Cc, nh, stat2);
    if (mode == 2) {
        k_z<<<256, 128, 0, stream>>>(acth, Mt, Cc, zbuf, stat2);
    } else {
        k_zpre_stats<<<512, 256, 0, stream>>>(x, cen, lw, rw, linw, Mt, Cc,
                                              zbuf, stat2);
    }
    k_out2<<<256, 256, 0, stream>>>(zbuf, stat2, g2, b2, nh, fzc, hW, hb, outp);
}

// Round 8
// 167.783 us; speedup vs baseline: 2.3125x; 1.0702x over previous
//
#include <hip/hip_runtime.h>
#include <hip/hip_fp16.h>
#include <math.h>

#define B_N 131072

// ---------------- ws layout (float offsets) ----------------
#define WS_STAT1 0
#define ST1_SZ   (64 * 352)          // 22528
#define WS_MT    22528               // Mt[64][20]
#define WS_C     23808               // C[20]
#define WS_STAT2 23840               // 64 stripes x 40 -> 26400
#define WS_NH    26400               // nhu[200], nhl[200] -> 26800
#define WS_ACTH  26816               // act fp16 [B][64]  (B*32 floats of storage)
#define WS_Z     (26816 + (size_t)B_N * 32)   // z col-major [20][B]
#define WS_END   (WS_Z + (size_t)B_N * 20)

struct alignas(16) H8 { __half2 a, b, c, d; };

__device__ __forceinline__ float gelu_exact(float v) {
    return 0.5f * v * (1.0f + erff(v * 0.70710678118654752440f));
}

// ---------------- pass 1: RBF -> act (fp16 store) + act moments ----------------
__global__ __launch_bounds__(256) void k_act_moments(
    const float* __restrict__ x, const float* __restrict__ cen,
    const float* __restrict__ lw, const float* __restrict__ rw,
    const float* __restrict__ linw, __half* __restrict__ act_h,
    float* __restrict__ stat1, int store)
{
    __shared__ float sAcc[4][8][44];
    const int t = threadIdx.x;
    const int g = t & 7;
    const int rl = t >> 3;

    float c_[8], nh_[8], w_[8];
#pragma unroll
    for (int k = 0; k < 8; ++k) {
        c_[k] = cen[g * 8 + k];
        float s = expf(lw[g * 8 + k]) + 1e-6f;
        nh_[k] = -0.5f / (s * s);
        w_[k] = rw[g * 8 + k];
    }
    const float lin = linw[g];

    float sumA[8], P[36];
#pragma unroll
    for (int f = 0; f < 8; ++f) sumA[f] = 0.0f;
#pragma unroll
    for (int i = 0; i < 36; ++i) P[i] = 0.0f;

#pragma unroll 1
    for (int row = blockIdx.x * 32 + rl; row < B_N; row += gridDim.x * 32) {
        const float* xr = x + (size_t)row * 64 + g * 8;
        float4 v0 = *(const float4*)(xr);
        float4 v1 = *(const float4*)(xr + 4);
        float xv[8] = {v0.x, v0.y, v0.z, v0.w, v1.x, v1.y, v1.z, v1.w};
        float act[8];
#pragma unroll
        for (int f = 0; f < 8; ++f) {
            float v = xv[f];
            float a = lin * v;
#pragma unroll
            for (int k = 0; k < 8; ++k) {
                float d = v - c_[k];
                a += w_[k] * __expf(d * d * nh_[k]);
            }
            act[f] = a;
        }
        if (store) {
            H8 h;
            h.a = __floats2half2_rn(act[0], act[1]);
            h.b = __floats2half2_rn(act[2], act[3]);
            h.c = __floats2half2_rn(act[4], act[5]);
            h.d = __floats2half2_rn(act[6], act[7]);
            *(H8*)(act_h + (size_t)row * 64 + g * 8) = h;
        }
        int idx = 0;
#pragma unroll
        for (int f = 0; f < 8; ++f) {
            sumA[f] += act[f];
#pragma unroll
            for (int f2 = 0; f2 <= f; ++f2) { P[idx] += act[f] * act[f2]; ++idx; }
        }
    }

#pragma unroll
    for (int off = 32; off >= 8; off >>= 1) {
#pragma unroll
        for (int f = 0; f < 8; ++f) sumA[f] += __shfl_down(sumA[f], off, 64);
#pragma unroll
        for (int i = 0; i < 36; ++i) P[i] += __shfl_down(P[i], off, 64);
    }
    const int wave = t >> 6, lane = t & 63;
    if (lane < 8) {   // lane == g
        float* dst = &sAcc[wave][lane][0];
#pragma unroll
        for (int f = 0; f < 8; ++f) dst[f] = sumA[f];
#pragma unroll
        for (int i = 0; i < 36; ++i) dst[8 + i] = P[i];
    }
    __syncthreads();
    for (int i = t; i < 352; i += 256) {
        int gg = i / 44, v = i % 44;
        float s = sAcc[0][gg][v] + sAcc[1][gg][v] + sAcc[2][gg][v] + sAcc[3][gg][v];
        atomicAdd(&stat1[(blockIdx.x & 63) * 352 + i], s);
    }
}

// ---------------- build: BN1 fold -> Mt/C, fuzzy tables, zero stat2 ----------------
__global__ __launch_bounds__(256) void k_build(
    const float* __restrict__ stat1, const float* __restrict__ fpW,
    const float* __restrict__ fpb, const float* __restrict__ g1,
    const float* __restrict__ b1, const float* __restrict__ Wp,
    const float* __restrict__ pb, const float* __restrict__ lsu,
    const float* __restrict__ lsl,
    float* __restrict__ Mt, float* __restrict__ Cc, float* __restrict__ nh,
    float* __restrict__ stat2)
{
    __shared__ float Am[8][8];
    __shared__ float Sg[8][36];
    __shared__ float a_[128], bb_[128];
    const int t = threadIdx.x;
    for (int i = t; i < 352; i += 256) {
        float s = 0.0f;
        for (int st = 0; st < 64; ++st) s += stat1[st * 352 + i];
        float m = s * (1.0f / B_N);
        int g = i / 44, v = i % 44;
        if (v < 8) Am[g][v] = m; else Sg[g][v - 8] = m;
    }
    __syncthreads();
    if (t < 128) {
        const int g = t >> 4;
        float wv[8];
#pragma unroll
        for (int f = 0; f < 8; ++f) wv[f] = Wp[t * 8 + f];
        float dot = 0.0f;
#pragma unroll
        for (int f = 0; f < 8; ++f) dot += wv[f] * Am[g][f];
        const float pbv = pb[t];
        const float mu = pbv + dot;
        float e2 = pbv * pbv + 2.0f * pbv * dot;
        int idx = 0;
#pragma unroll
        for (int f = 0; f < 8; ++f)
#pragma unroll
            for (int f2 = 0; f2 <= f; ++f2) {
                float c2 = (f2 == f) ? 1.0f : 2.0f;
                e2 += c2 * wv[f] * wv[f2] * Sg[g][idx]; ++idx;
            }
        const float var = fmaxf(e2 - mu * mu, 0.0f);
        const float a = g1[t] * rsqrtf(var + 1e-5f);
        a_[t] = a;
        bb_[t] = b1[t] - mu * a;
    }
    __syncthreads();
    for (int i = t; i < 1280; i += 256) {
        int gf = i / 20, j = i % 20;
        int g = gf >> 3, f = gf & 7;
        float m = 0.0f;
        for (int o = 0; o < 16; ++o) {
            int c = g * 16 + o;
            m += fpW[j * 128 + c] * a_[c] * Wp[c * 8 + f];
        }
        Mt[i] = m;
    }
    if (t < 20) {
        float cj = fpb[t];
        for (int c = 0; c < 128; ++c)
            cj += fpW[t * 128 + c] * (a_[c] * pb[c] + bb_[c]);
        Cc[t] = cj;
    }
    for (int i = t; i < 200; i += 256) {
        float su = expf(lsu[i]) + 1e-6f;
        float sl = fminf(expf(lsl[i]) + 1e-6f, 0.9f * su);
        nh[i] = -0.5f / (su * su);
        nh[200 + i] = -0.5f / (sl * sl);
    }
    for (int i = t; i < 2560; i += 256) stat2[i] = 0.0f;
}

// ---------------- pass 2: z = act_h · Mt + C, scalar-Mt, 1 row/thread ----------------
// 512 blocks x 256 threads; Mt/Cc read via uniform (scalar) loads — no LDS staging
__global__ __launch_bounds__(256) void k_z(
    const __half* __restrict__ act_h, const float* __restrict__ Mt,
    const float* __restrict__ Cc, float* __restrict__ zout,
    float* __restrict__ stat2)
{
    __shared__ float sRed[4][40];
    const int t = threadIdx.x;
    const int row = blockIdx.x * 256 + t;

    float zp[20];
#pragma unroll
    for (int j = 0; j < 20; ++j) zp[j] = Cc[j];   // uniform -> s_load

#pragma unroll 1
    for (int g = 0; g < 8; ++g) {
        const H8 h = *(const H8*)(act_h + (size_t)row * 64 + g * 8);
        float2 f0 = __half22float2(h.a), f1 = __half22float2(h.b);
        float2 f2 = __half22float2(h.c), f3 = __half22float2(h.d);
        float a[8] = {f0.x, f0.y, f1.x, f1.y, f2.x, f2.y, f3.x, f3.y};
#pragma unroll
        for (int f = 0; f < 8; ++f) {
            const float* m = Mt + (g * 8 + f) * 20;   // uniform base
            float av = a[f];
#pragma unroll
            for (int j = 0; j < 20; ++j) zp[j] += av * m[j];   // v_fmac v,s,v
        }
    }

    // coalesced col-major store
#pragma unroll
    for (int j = 0; j < 20; ++j) zout[(size_t)j * B_N + row] = zp[j];

    // BN2 partial stats: wave shuffle -> LDS -> striped atomics
    float s_[20], q_[20];
#pragma unroll
    for (int j = 0; j < 20; ++j) { s_[j] = zp[j]; q_[j] = zp[j] * zp[j]; }
#pragma unroll
    for (int off = 32; off >= 1; off >>= 1) {
#pragma unroll
        for (int j = 0; j < 20; ++j) {
            s_[j] += __shfl_down(s_[j], off, 64);
            q_[j] += __shfl_down(q_[j], off, 64);
        }
    }
    const int wave = t >> 6, lane = t & 63;
    if (lane == 0) {
#pragma unroll
        for (int j = 0; j < 20; ++j) { sRed[wave][j] = s_[j]; sRed[wave][20 + j] = q_[j]; }
    }
    __syncthreads();
    if (t < 40) {
        float v = sRed[0][t] + sRed[1][t] + sRed[2][t] + sRed[3][t];
        atomicAdd(&stat2[(blockIdx.x & 63) * 40 + t], v);
    }
}

// ---------------- fallback pass 2 (ws too small): recompute RBF ----------------
__global__ __launch_bounds__(256) void k_zpre_stats(
    const float* __restrict__ x, const float* __restrict__ cen,
    const float* __restrict__ lw, const float* __restrict__ rw,
    const float* __restrict__ linw, const float* __restrict__ Mt,
    const float* __restrict__ Cc, float* __restrict__ zout,
    float* __restrict__ stat2)
{
    __shared__ __align__(16) float4 sRbf[64];
    __shared__ float sLin[8], sC[20];
    __shared__ __align__(16) float sMt[1280];
    __shared__ float sRed[4][40];
    const int t = threadIdx.x;
    if (t < 64) {
        float s = expf(lw[t]) + 1e-6f;
        sRbf[t] = make_float4(cen[t], rw[t], -0.5f / (s * s), 0.0f);
    }
    if (t < 8)  sLin[t] = linw[t];
    if (t < 20) sC[t] = Cc[t];
    for (int i = t; i < 1280; i += 256) sMt[i] = Mt[i];
    __syncthreads();
    const int row = blockIdx.x * 256 + t;
    const float* xr = x + (size_t)row * 64;
    float zp[20];
#pragma unroll
    for (int j = 0; j < 20; ++j) zp[j] = sC[j];
#pragma unroll 1
    for (int g = 0; g < 8; ++g) {
        float4 v0 = *(const float4*)(xr + g * 8);
        float4 v1 = *(const float4*)(xr + g * 8 + 4);
        float xv[8] = {v0.x, v0.y, v0.z, v0.w, v1.x, v1.y, v1.z, v1.w};
        float act[8];
        float lin = sLin[g];
#pragma unroll
        for (int f = 0; f < 8; ++f) act[f] = lin * xv[f];
#pragma unroll 1
        for (int k = 0; k < 8; ++k) {
            float4 p = sRbf[g * 8 + k];
#pragma unroll
            for (int f = 0; f < 8; ++f) {
                float d = xv[f] - p.x;
                act[f] += p.y * __expf(d * d * p.z);
            }
        }
#pragma unroll 1
        for (int f = 0; f < 8; ++f) {
            float av = act[f];
            const float4* m4 = (const float4*)(sMt + (g * 8 + f) * 20);
            float4 ma = m4[0], mb = m4[1], mc = m4[2], md = m4[3], me = m4[4];
            zp[0] += av * ma.x; zp[1] += av * ma.y; zp[2] += av * ma.z; zp[3] += av * ma.w;
            zp[4] += av * mb.x; zp[5] += av * mb.y; zp[6] += av * mb.z; zp[7] += av * mb.w;
            zp[8] += av * mc.x; zp[9] += av * mc.y; zp[10] += av * mc.z; zp[11] += av * mc.w;
            zp[12] += av * md.x; zp[13] += av * md.y; zp[14] += av * md.z; zp[15] += av * md.w;
            zp[16] += av * me.x; zp[17] += av * me.y; zp[18] += av * me.z; zp[19] += av * me.w;
        }
    }
#pragma unroll
    for (int j = 0; j < 20; ++j) zout[(size_t)j * B_N + row] = zp[j];
    float s_[20], q_[20];
#pragma unroll
    for (int j = 0; j < 20; ++j) { s_[j] = zp[j]; q_[j] = zp[j] * zp[j]; }
#pragma unroll
    for (int off = 32; off >= 1; off >>= 1) {
#pragma unroll
        for (int j = 0; j < 20; ++j) {
            s_[j] += __shfl_down(s_[j], off, 64);
            q_[j] += __shfl_down(q_[j], off, 64);
        }
    }
    const int wave = t >> 6, lane = t & 63;
    if (lane == 0) {
#pragma unroll
        for (int j = 0; j < 20; ++j) { sRed[wave][j] = s_[j]; sRed[wave][20 + j] = q_[j]; }
    }
    __syncthreads();
    if (t < 40) {
        float v = sRed[0][t] + sRed[1][t] + sRed[2][t] + sRed[3][t];
        atomicAdd(&stat2[(blockIdx.x & 63) * 40 + t], v);
    }
}

// ---------------- pass 3: BN2 + GELU + fuzzy + head, scalar params, 1 row/thread ----------------
// 512 blocks x 256 threads; fuzzy tables read via uniform (scalar) loads
__global__ __launch_bounds__(256) void k_out(
    const float* __restrict__ zin, const float* __restrict__ stat2,
    const float* __restrict__ g2, const float* __restrict__ b2,
    const float* __restrict__ nh, const float* __restrict__ fzc,
    const float* __restrict__ hW, const float* __restrict__ hb,
    float* __restrict__ out)
{
    __shared__ float sT[40], sSc[20], sSh[20];
    const int t = threadIdx.x;
    if (t < 40) {
        float s = 0.0f;
        for (int st = 0; st < 64; ++st) s += stat2[st * 40 + t];
        sT[t] = s;
    }
    __syncthreads();
    if (t < 20) {
        float mu = sT[t] * (1.0f / B_N);
        float var = fmaxf(sT[20 + t] * (1.0f / B_N) - mu * mu, 0.0f);
        float sc = g2[t] * rsqrtf(var + 1e-5f);
        sSc[t] = sc;
        sSh[t] = b2[t] - mu * sc;
    }
    __syncthreads();

    const int row = blockIdx.x * 256 + t;
    float z[20];
#pragma unroll
    for (int j = 0; j < 20; ++j) {
        float v = zin[(size_t)j * B_N + row];       // coalesced per column
        z[j] = gelu_exact(sSc[j] * v + sSh[j]);
    }
    float acc = hb[0];
#pragma unroll 1
    for (int r = 0; r < 10; ++r) {
        float u = 0.0f, l = 0.0f;
#pragma unroll
        for (int j = 0; j < 20; ++j) {
            float cx = fzc[r * 20 + j];             // uniform -> s_load
            float pu = nh[r * 20 + j];
            float pl = nh[200 + r * 20 + j];
            float d = z[j] - cx;
            float dd = d * d;
            u += __expf(dd * pu);
            l += __expf(dd * pl);
        }
        acc += hW[r] * 0.025f * (u + l);
    }
    out[row] = acc;
}

// ---------------- launcher ----------------
extern "C" void kernel_launch(void* const* d_in, const int* in_sizes, int n_in,
                              void* d_out, int out_size, void* d_ws, size_t ws_size,
                              hipStream_t stream) {
    const float* x    = (const float*)d_in[0];
    const float* cen  = (const float*)d_in[1];
    const float* lw   = (const float*)d_in[2];
    const float* rw   = (const float*)d_in[3];
    const float* linw = (const float*)d_in[4];
    const float* Wp   = (const float*)d_in[5];
    const float* pb   = (const float*)d_in[6];
    const float* g1   = (const float*)d_in[7];
    const float* b1   = (const float*)d_in[8];
    const float* fpW  = (const float*)d_in[9];
    const float* fpb  = (const float*)d_in[10];
    const float* g2   = (const float*)d_in[11];
    const float* b2   = (const float*)d_in[12];
    const float* fzc  = (const float*)d_in[13];
    const float* lsu  = (const float*)d_in[14];
    const float* lsl  = (const float*)d_in[15];
    const float* hW   = (const float*)d_in[16];
    const float* hb   = (const float*)d_in[17];

    float* ws    = (float*)d_ws;
    float* stat1 = ws + WS_STAT1;
    float* Mt    = ws + WS_MT;
    float* Cc    = ws + WS_C;
    float* stat2 = ws + WS_STAT2;
    float* nh    = ws + WS_NH;
    __half* acth = (__half*)(ws + WS_ACTH);
    float* zbuf  = ws + WS_Z;
    float* outp  = (float*)d_out;

    const size_t needFull = WS_END * sizeof(float);
    const int mode = (ws_size >= needFull) ? 2 : 1;
    if (mode == 1) zbuf = ws + WS_ACTH;   // no act buffer in fallback mode

    hipMemsetAsync(stat1, 0, (size_t)ST1_SZ * sizeof(float), stream);
    k_act_moments<<<1024, 256, 0, stream>>>(x, cen, lw, rw, linw, acth, stat1,
                                            mode == 2 ? 1 : 0);
    k_build<<<1, 256, 0, stream>>>(stat1, fpW, fpb, g1, b1, Wp, pb, lsu, lsl,
                                   Mt, Cc, nh, stat2);
    if (mode == 2) {
        k_z<<<512, 256, 0, stream>>>(acth, Mt, Cc, zbuf, stat2);
    } else {
        k_zpre_stats<<<512, 256, 0, stream>>>(x, cen, lw, rw, linw, Mt, Cc,
                                              zbuf, stat2);
    }
    k_out<<<512, 256, 0, stream>>>(zbuf, stat2, g2, b2, nh, fzc, hW, hb, outp);
}

// Round 9
// 166.245 us; speedup vs baseline: 2.3339x; 1.0093x over previous
//
#include <hip/hip_runtime.h>
#include <hip/hip_fp16.h>
#include <math.h>

#define B_N 131072

// ---------------- ws layout (float offsets) ----------------
#define WS_STAT1 0
#define ST1_SZ   (64 * 352)          // 22528
#define WS_MT    22528               // Mt[64][20]
#define WS_C     23808               // C[20]
#define WS_STAT2 23840               // 64 stripes x 40 -> 26400
#define WS_NH    26400               // nhu[200], nhl[200] -> 26800
#define WS_ACTH  26816               // act fp16 [B][64]  (B*32 floats of storage)
#define WS_Z     (26816 + (size_t)B_N * 32)   // z col-major [20][B]
#define WS_END   (WS_Z + (size_t)B_N * 20)

struct alignas(16) H8 { __half2 a, b, c, d; };

__device__ __forceinline__ float gelu_exact(float v) {
    return 0.5f * v * (1.0f + erff(v * 0.70710678118654752440f));
}

// ---------------- pass 1: RBF -> act (fp16 store) + act moments ----------------
// Fast path: uniform centre grid + shared width per group -> 2 exps + Horner
// instead of 8 exps per feature. Runtime-verified, wave-uniform branch.
__global__ __launch_bounds__(256) void k_act_moments(
    const float* __restrict__ x, const float* __restrict__ cen,
    const float* __restrict__ lw, const float* __restrict__ rw,
    const float* __restrict__ linw, __half* __restrict__ act_h,
    float* __restrict__ stat1, int store)
{
    __shared__ float sAcc[4][8][44];
    const int t = threadIdx.x;
    const int g = t & 7;
    const int rl = t >> 3;

    float c_[8], nh_[8], w_[8];
#pragma unroll
    for (int k = 0; k < 8; ++k) {
        c_[k] = cen[g * 8 + k];
        float s = expf(lw[g * 8 + k]) + 1e-6f;
        nh_[k] = -0.5f / (s * s);
        w_[k] = rw[g * 8 + k];
    }
    const float lin = linw[g];
    const float c0 = c_[0], nh0 = nh_[0];
    const float delta = c_[1] - c_[0];

    // uniformity check (per lane, then wave-uniform via __all)
    bool uni = true;
#pragma unroll
    for (int k = 0; k < 8; ++k) {
        float ck = c0 + (float)k * delta;
        uni = uni && (fabsf(c_[k] - ck) <= 1e-5f * (1.0f + fabsf(ck)));
        uni = uni && (fabsf(nh_[k] - nh0) <= 1e-6f * fabsf(nh0));
    }
    const bool fast = (bool)__all((int)uni);

    float W_[8];
    float k1 = 0.0f;
    if (fast) {
        k1 = -2.0f * delta * nh0;
#pragma unroll
        for (int k = 0; k < 8; ++k) {
            float kd = (float)k * delta;
            W_[k] = w_[k] * __expf(nh0 * kd * kd);
        }
    }

    float sumA[8], P[36];
#pragma unroll
    for (int f = 0; f < 8; ++f) sumA[f] = 0.0f;
#pragma unroll
    for (int i = 0; i < 36; ++i) P[i] = 0.0f;

    if (fast) {
#pragma unroll 1
        for (int row = blockIdx.x * 32 + rl; row < B_N; row += gridDim.x * 32) {
            const float* xr = x + (size_t)row * 64 + g * 8;
            float4 v0 = *(const float4*)(xr);
            float4 v1 = *(const float4*)(xr + 4);
            float xv[8] = {v0.x, v0.y, v0.z, v0.w, v1.x, v1.y, v1.z, v1.w};
            float act[8];
#pragma unroll
            for (int f = 0; f < 8; ++f) {
                float v = xv[f];
                float dv = v - c0;
                float E0 = __expf(nh0 * dv * dv);
                float T  = __expf(k1 * dv);
                float poly = W_[7];
#pragma unroll
                for (int k = 6; k >= 0; --k) poly = poly * T + W_[k];
                act[f] = lin * v + E0 * poly;
            }
            if (store) {
                H8 h;
                h.a = __floats2half2_rn(act[0], act[1]);
                h.b = __floats2half2_rn(act[2], act[3]);
                h.c = __floats2half2_rn(act[4], act[5]);
                h.d = __floats2half2_rn(act[6], act[7]);
                *(H8*)(act_h + (size_t)row * 64 + g * 8) = h;
            }
            int idx = 0;
#pragma unroll
            for (int f = 0; f < 8; ++f) {
                sumA[f] += act[f];
#pragma unroll
                for (int f2 = 0; f2 <= f; ++f2) { P[idx] += act[f] * act[f2]; ++idx; }
            }
        }
    } else {
#pragma unroll 1
        for (int row = blockIdx.x * 32 + rl; row < B_N; row += gridDim.x * 32) {
            const float* xr = x + (size_t)row * 64 + g * 8;
            float4 v0 = *(const float4*)(xr);
            float4 v1 = *(const float4*)(xr + 4);
            float xv[8] = {v0.x, v0.y, v0.z, v0.w, v1.x, v1.y, v1.z, v1.w};
            float act[8];
#pragma unroll
            for (int f = 0; f < 8; ++f) {
                float v = xv[f];
                float a = lin * v;
#pragma unroll
                for (int k = 0; k < 8; ++k) {
                    float d = v - c_[k];
                    a += w_[k] * __expf(d * d * nh_[k]);
                }
                act[f] = a;
            }
            if (store) {
                H8 h;
                h.a = __floats2half2_rn(act[0], act[1]);
                h.b = __floats2half2_rn(act[2], act[3]);
                h.c = __floats2half2_rn(act[4], act[5]);
                h.d = __floats2half2_rn(act[6], act[7]);
                *(H8*)(act_h + (size_t)row * 64 + g * 8) = h;
            }
            int idx = 0;
#pragma unroll
            for (int f = 0; f < 8; ++f) {
                sumA[f] += act[f];
#pragma unroll
                for (int f2 = 0; f2 <= f; ++f2) { P[idx] += act[f] * act[f2]; ++idx; }
            }
        }
    }

#pragma unroll
    for (int off = 32; off >= 8; off >>= 1) {
#pragma unroll
        for (int f = 0; f < 8; ++f) sumA[f] += __shfl_down(sumA[f], off, 64);
#pragma unroll
        for (int i = 0; i < 36; ++i) P[i] += __shfl_down(P[i], off, 64);
    }
    const int wave = t >> 6, lane = t & 63;
    if (lane < 8) {   // lane == g
        float* dst = &sAcc[wave][lane][0];
#pragma unroll
        for (int f = 0; f < 8; ++f) dst[f] = sumA[f];
#pragma unroll
        for (int i = 0; i < 36; ++i) dst[8 + i] = P[i];
    }
    __syncthreads();
    for (int i = t; i < 352; i += 256) {
        int gg = i / 44, v = i % 44;
        float s = sAcc[0][gg][v] + sAcc[1][gg][v] + sAcc[2][gg][v] + sAcc[3][gg][v];
        atomicAdd(&stat1[(blockIdx.x & 63) * 352 + i], s);
    }
}

// ---------------- build: BN1 fold -> Mt/C, fuzzy tables, zero stat2 ----------------
__global__ __launch_bounds__(256) void k_build(
    const float* __restrict__ stat1, const float* __restrict__ fpW,
    const float* __restrict__ fpb, const float* __restrict__ g1,
    const float* __restrict__ b1, const float* __restrict__ Wp,
    const float* __restrict__ pb, const float* __restrict__ lsu,
    const float* __restrict__ lsl,
    float* __restrict__ Mt, float* __restrict__ Cc, float* __restrict__ nh,
    float* __restrict__ stat2)
{
    __shared__ float Am[8][8];
    __shared__ float Sg[8][36];
    __shared__ float a_[128], bb_[128];
    const int t = threadIdx.x;
    for (int i = t; i < 352; i += 256) {
        float s = 0.0f;
        for (int st = 0; st < 64; ++st) s += stat1[st * 352 + i];
        float m = s * (1.0f / B_N);
        int g = i / 44, v = i % 44;
        if (v < 8) Am[g][v] = m; else Sg[g][v - 8] = m;
    }
    __syncthreads();
    if (t < 128) {
        const int g = t >> 4;
        float wv[8];
#pragma unroll
        for (int f = 0; f < 8; ++f) wv[f] = Wp[t * 8 + f];
        float dot = 0.0f;
#pragma unroll
        for (int f = 0; f < 8; ++f) dot += wv[f] * Am[g][f];
        const float pbv = pb[t];
        const float mu = pbv + dot;
        float e2 = pbv * pbv + 2.0f * pbv * dot;
        int idx = 0;
#pragma unroll
        for (int f = 0; f < 8; ++f)
#pragma unroll
            for (int f2 = 0; f2 <= f; ++f2) {
                float c2 = (f2 == f) ? 1.0f : 2.0f;
                e2 += c2 * wv[f] * wv[f2] * Sg[g][idx]; ++idx;
            }
        const float var = fmaxf(e2 - mu * mu, 0.0f);
        const float a = g1[t] * rsqrtf(var + 1e-5f);
        a_[t] = a;
        bb_[t] = b1[t] - mu * a;
    }
    __syncthreads();
    for (int i = t; i < 1280; i += 256) {
        int gf = i / 20, j = i % 20;
        int g = gf >> 3, f = gf & 7;
        float m = 0.0f;
        for (int o = 0; o < 16; ++o) {
            int c = g * 16 + o;
            m += fpW[j * 128 + c] * a_[c] * Wp[c * 8 + f];
        }
        Mt[i] = m;
    }
    if (t < 20) {
        float cj = fpb[t];
        for (int c = 0; c < 128; ++c)
            cj += fpW[t * 128 + c] * (a_[c] * pb[c] + bb_[c]);
        Cc[t] = cj;
    }
    for (int i = t; i < 200; i += 256) {
        float su = expf(lsu[i]) + 1e-6f;
        float sl = fminf(expf(lsl[i]) + 1e-6f, 0.9f * su);
        nh[i] = -0.5f / (su * su);
        nh[200 + i] = -0.5f / (sl * sl);
    }
    for (int i = t; i < 2560; i += 256) stat2[i] = 0.0f;
}

// ---------------- pass 2: z = act_h · Mt + C, scalar-Mt, 1 row/thread ----------------
__global__ __launch_bounds__(256) void k_z(
    const __half* __restrict__ act_h, const float* __restrict__ Mt,
    const float* __restrict__ Cc, float* __restrict__ zout,
    float* __restrict__ stat2)
{
    __shared__ float sRed[4][40];
    const int t = threadIdx.x;
    const int row = blockIdx.x * 256 + t;

    float zp[20];
#pragma unroll
    for (int j = 0; j < 20; ++j) zp[j] = Cc[j];   // uniform -> s_load

#pragma unroll 1
    for (int g = 0; g < 8; ++g) {
        const H8 h = *(const H8*)(act_h + (size_t)row * 64 + g * 8);
        float2 f0 = __half22float2(h.a), f1 = __half22float2(h.b);
        float2 f2 = __half22float2(h.c), f3 = __half22float2(h.d);
        float a[8] = {f0.x, f0.y, f1.x, f1.y, f2.x, f2.y, f3.x, f3.y};
#pragma unroll
        for (int f = 0; f < 8; ++f) {
            const float* m = Mt + (g * 8 + f) * 20;   // uniform base
            float av = a[f];
#pragma unroll
            for (int j = 0; j < 20; ++j) zp[j] += av * m[j];   // v_fmac v,s,v
        }
    }

#pragma unroll
    for (int j = 0; j < 20; ++j) zout[(size_t)j * B_N + row] = zp[j];

    float s_[20], q_[20];
#pragma unroll
    for (int j = 0; j < 20; ++j) { s_[j] = zp[j]; q_[j] = zp[j] * zp[j]; }
#pragma unroll
    for (int off = 32; off >= 1; off >>= 1) {
#pragma unroll
        for (int j = 0; j < 20; ++j) {
            s_[j] += __shfl_down(s_[j], off, 64);
            q_[j] += __shfl_down(q_[j], off, 64);
        }
    }
    const int wave = t >> 6, lane = t & 63;
    if (lane == 0) {
#pragma unroll
        for (int j = 0; j < 20; ++j) { sRed[wave][j] = s_[j]; sRed[wave][20 + j] = q_[j]; }
    }
    __syncthreads();
    if (t < 40) {
        float v = sRed[0][t] + sRed[1][t] + sRed[2][t] + sRed[3][t];
        atomicAdd(&stat2[(blockIdx.x & 63) * 40 + t], v);
    }
}

// ---------------- fallback pass 2 (ws too small): recompute RBF ----------------
__global__ __launch_bounds__(256) void k_zpre_stats(
    const float* __restrict__ x, const float* __restrict__ cen,
    const float* __restrict__ lw, const float* __restrict__ rw,
    const float* __restrict__ linw, const float* __restrict__ Mt,
    const float* __restrict__ Cc, float* __restrict__ zout,
    float* __restrict__ stat2)
{
    __shared__ __align__(16) float4 sRbf[64];
    __shared__ float sLin[8], sC[20];
    __shared__ __align__(16) float sMt[1280];
    __shared__ float sRed[4][40];
    const int t = threadIdx.x;
    if (t < 64) {
        float s = expf(lw[t]) + 1e-6f;
        sRbf[t] = make_float4(cen[t], rw[t], -0.5f / (s * s), 0.0f);
    }
    if (t < 8)  sLin[t] = linw[t];
    if (t < 20) sC[t] = Cc[t];
    for (int i = t; i < 1280; i += 256) sMt[i] = Mt[i];
    __syncthreads();
    const int row = blockIdx.x * 256 + t;
    const float* xr = x + (size_t)row * 64;
    float zp[20];
#pragma unroll
    for (int j = 0; j < 20; ++j) zp[j] = sC[j];
#pragma unroll 1
    for (int g = 0; g < 8; ++g) {
        float4 v0 = *(const float4*)(xr + g * 8);
        float4 v1 = *(const float4*)(xr + g * 8 + 4);
        float xv[8] = {v0.x, v0.y, v0.z, v0.w, v1.x, v1.y, v1.z, v1.w};
        float act[8];
        float lin = sLin[g];
#pragma unroll
        for (int f = 0; f < 8; ++f) act[f] = lin * xv[f];
#pragma unroll 1
        for (int k = 0; k < 8; ++k) {
            float4 p = sRbf[g * 8 + k];
#pragma unroll
            for (int f = 0; f < 8; ++f) {
                float d = xv[f] - p.x;
                act[f] += p.y * __expf(d * d * p.z);
            }
        }
#pragma unroll 1
        for (int f = 0; f < 8; ++f) {
            float av = act[f];
            const float4* m4 = (const float4*)(sMt + (g * 8 + f) * 20);
            float4 ma = m4[0], mb = m4[1], mc = m4[2], md = m4[3], me = m4[4];
            zp[0] += av * ma.x; zp[1] += av * ma.y; zp[2] += av * ma.z; zp[3] += av * ma.w;
            zp[4] += av * mb.x; zp[5] += av * mb.y; zp[6] += av * mb.z; zp[7] += av * mb.w;
            zp[8] += av * mc.x; zp[9] += av * mc.y; zp[10] += av * mc.z; zp[11] += av * mc.w;
            zp[12] += av * md.x; zp[13] += av * md.y; zp[14] += av * md.z; zp[15] += av * md.w;
            zp[16] += av * me.x; zp[17] += av * me.y; zp[18] += av * me.z; zp[19] += av * me.w;
        }
    }
#pragma unroll
    for (int j = 0; j < 20; ++j) zout[(size_t)j * B_N + row] = zp[j];
    float s_[20], q_[20];
#pragma unroll
    for (int j = 0; j < 20; ++j) { s_[j] = zp[j]; q_[j] = zp[j] * zp[j]; }
#pragma unroll
    for (int off = 32; off >= 1; off >>= 1) {
#pragma unroll
        for (int j = 0; j < 20; ++j) {
            s_[j] += __shfl_down(s_[j], off, 64);
            q_[j] += __shfl_down(q_[j], off, 64);
        }
    }
    const int wave = t >> 6, lane = t & 63;
    if (lane == 0) {
#pragma unroll
        for (int j = 0; j < 20; ++j) { sRed[wave][j] = s_[j]; sRed[wave][20 + j] = q_[j]; }
    }
    __syncthreads();
    if (t < 40) {
        float v = sRed[0][t] + sRed[1][t] + sRed[2][t] + sRed[3][t];
        atomicAdd(&stat2[(blockIdx.x & 63) * 40 + t], v);
    }
}

// ---------------- pass 3: BN2 + GELU + fuzzy + head, scalar params ----------------
__global__ __launch_bounds__(256) void k_out(
    const float* __restrict__ zin, const float* __restrict__ stat2,
    const float* __restrict__ g2, const float* __restrict__ b2,
    const float* __restrict__ nh, const float* __restrict__ fzc,
    const float* __restrict__ hW, const float* __restrict__ hb,
    float* __restrict__ out)
{
    __shared__ float sT[40], sSc[20], sSh[20];
    const int t = threadIdx.x;
    if (t < 40) {
        float s = 0.0f;
        for (int st = 0; st < 64; ++st) s += stat2[st * 40 + t];
        sT[t] = s;
    }
    __syncthreads();
    if (t < 20) {
        float mu = sT[t] * (1.0f / B_N);
        float var = fmaxf(sT[20 + t] * (1.0f / B_N) - mu * mu, 0.0f);
        float sc = g2[t] * rsqrtf(var + 1e-5f);
        sSc[t] = sc;
        sSh[t] = b2[t] - mu * sc;
    }
    __syncthreads();

    const int row = blockIdx.x * 256 + t;
    float z[20];
#pragma unroll
    for (int j = 0; j < 20; ++j) {
        float v = zin[(size_t)j * B_N + row];
        z[j] = gelu_exact(sSc[j] * v + sSh[j]);
    }
    float acc = hb[0];
#pragma unroll 1
    for (int r = 0; r < 10; ++r) {
        float u = 0.0f, l = 0.0f;
#pragma unroll
        for (int j = 0; j < 20; ++j) {
            float cx = fzc[r * 20 + j];
            float pu = nh[r * 20 + j];
            float pl = nh[200 + r * 20 + j];
            float d = z[j] - cx;
            float dd = d * d;
            u += __expf(dd * pu);
            l += __expf(dd * pl);
        }
        acc += hW[r] * 0.025f * (u + l);
    }
    out[row] = acc;
}

// ---------------- launcher ----------------
extern "C" void kernel_launch(void* const* d_in, const int* in_sizes, int n_in,
                              void* d_out, int out_size, void* d_ws, size_t ws_size,
                              hipStream_t stream) {
    const float* x    = (const float*)d_in[0];
    const float* cen  = (const float*)d_in[1];
    const float* lw   = (const float*)d_in[2];
    const float* rw   = (const float*)d_in[3];
    const float* linw = (const float*)d_in[4];
    const float* Wp   = (const float*)d_in[5];
    const float* pb   = (const float*)d_in[6];
    const float* g1   = (const float*)d_in[7];
    const float* b1   = (const float*)d_in[8];
    const float* fpW  = (const float*)d_in[9];
    const float* fpb  = (const float*)d_in[10];
    const float* g2   = (const float*)d_in[11];
    const float* b2   = (const float*)d_in[12];
    const float* fzc  = (const float*)d_in[13];
    const float* lsu  = (const float*)d_in[14];
    const float* lsl  = (const float*)d_in[15];
    const float* hW   = (const float*)d_in[16];
    const float* hb   = (const float*)d_in[17];

    float* ws    = (float*)d_ws;
    float* stat1 = ws + WS_STAT1;
    float* Mt    = ws + WS_MT;
    float* Cc    = ws + WS_C;
    float* stat2 = ws + WS_STAT2;
    float* nh    = ws + WS_NH;
    __half* acth = (__half*)(ws + WS_ACTH);
    float* zbuf  = ws + WS_Z;
    float* outp  = (float*)d_out;

    const size_t needFull = WS_END * sizeof(float);
    const int mode = (ws_size >= needFull) ? 2 : 1;
    if (mode == 1) zbuf = ws + WS_ACTH;

    hipMemsetAsync(stat1, 0, (size_t)ST1_SZ * sizeof(float), stream);
    k_act_moments<<<1024, 256, 0, stream>>>(x, cen, lw, rw, linw, acth, stat1,
                                            mode == 2 ? 1 : 0);
    k_build<<<1, 256, 0, stream>>>(stat1, fpW, fpb, g1, b1, Wp, pb, lsu, lsl,
                                   Mt, Cc, nh, stat2);
    if (mode == 2) {
        k_z<<<512, 256, 0, stream>>>(acth, Mt, Cc, zbuf, stat2);
    } else {
        k_zpre_stats<<<512, 256, 0, stream>>>(x, cen, lw, rw, linw, Mt, Cc,
                                              zbuf, stat2);
    }
    k_out<<<512, 256, 0, stream>>>(zbuf, stat2, g2, b2, nh, fzc, hW, hb, outp);
}